// Round 3
// baseline (1091.710 us; speedup 1.0000x reference)
//
#include <hip/hip_runtime.h>
#include <hip/hip_bf16.h>

// PSHGCN on MI355X — round 8:
//  * place_edges restructured: was 1 block per 512-row bucket (489 blocks,
//    17% occupancy, latency-starved serial atomic chains, 170 us). Now each
//    bucket is split across 8 blocks (contiguous chunks, coalesced reads)
//    and the scatter loop is unrolled x4 (4 independent load->atomic->store
//    chains in flight). Grid 489 -> 3912 blocks.
//  * count_rows vectorized x4 (int4 row loads).
//  * SpMM / dense front-end unchanged from round 7.

typedef float f32x2 __attribute__((ext_vector_type(2)));
typedef float f32x4 __attribute__((ext_vector_type(4)));

__device__ inline unsigned short f2bf(float x) {
    unsigned b = __float_as_uint(x);
    unsigned r = (b + 0x7fffu + ((b >> 16) & 1u)) >> 16;
    return (unsigned short)r;
}
__device__ inline float bflo(unsigned u) { return __uint_as_float(u << 16); }
__device__ inline float bfhi(unsigned u) { return __uint_as_float(u & 0xffff0000u); }

// pack 4 floats -> 4 fp8 e4m3 bytes (a in byte0 .. d in byte3)
__device__ inline unsigned pk_fp8x4(float a, float b, float c, float d) {
    int v = __builtin_amdgcn_cvt_pk_fp8_f32(a, b, 0, false);
    v = __builtin_amdgcn_cvt_pk_fp8_f32(c, d, v, true);
    return (unsigned)v;
}

// ---------------- dense: M = Wp @ W1 (two 128x128x128) ----------------
__global__ __launch_bounds__(128) void fuse_w(const float* __restrict__ Wp0,
                                              const float* __restrict__ Wp1,
                                              const float* __restrict__ W1,
                                              float* __restrict__ M0,
                                              float* __restrict__ M1) {
    int m = blockIdx.x >> 7;
    int i = blockIdx.x & 127;
    const float* Wp = m ? Wp1 : Wp0;
    float* M = m ? M1 : M0;
    __shared__ float r[128];
    int t = threadIdx.x;
    r[t] = Wp[i * 128 + t];
    __syncthreads();
    float acc = 0.f;
    #pragma unroll 8
    for (int k = 0; k < 128; ++k) acc += r[k] * W1[k * 128 + t];
    M[i * 128 + t] = acc;
}

// ---- dense: Xbf/X8 = normalize(relu(xin @ M + b1))  (bf16 + fp8 out) ----
__global__ __launch_bounds__(256) void gemm_relu_norm(const float* __restrict__ xin,
                                                      const float* __restrict__ M,
                                                      const float* __restrict__ b1,
                                                      unsigned short* __restrict__ xbf,
                                                      unsigned char* __restrict__ x8,
                                                      int nrows) {
    __shared__ float Wl[64 * 128];
    __shared__ float xs[32 * 128];
    int t = threadIdx.x;
    long row0 = (long)blockIdx.x * 32;
    int rows_this = nrows - (int)row0;
    if (rows_this > 32) rows_this = 32;

    #pragma unroll
    for (int it = 0; it < 4; ++it) {
        int g4 = it * 256 + t;
        int g = g4 * 4;
        int rl = g >> 7, c = g & 127;
        float4 val = {0.f, 0.f, 0.f, 0.f};
        if (rl < rows_this) val = *(const float4*)(xin + (row0 + rl) * 128 + c);
        *(float4*)&xs[rl * 128 + c] = val;
    }

    int r0 = (t >> 5) * 4;
    int c0 = (t & 31) * 4;
    float acc[4][4];
    #pragma unroll
    for (int i = 0; i < 4; ++i)
        #pragma unroll
        for (int j = 0; j < 4; ++j) acc[i][j] = 0.f;

    for (int h = 0; h < 2; ++h) {
        __syncthreads();
        #pragma unroll
        for (int it = 0; it < 8; ++it) {
            int g4 = it * 256 + t;
            ((float4*)Wl)[g4] = ((const float4*)(M + h * 8192))[g4];
        }
        __syncthreads();
        #pragma unroll 4
        for (int k = 0; k < 64; ++k) {
            float4 w = *(float4*)&Wl[k * 128 + c0];
            int kk = h * 64 + k;
            #pragma unroll
            for (int i = 0; i < 4; ++i) {
                float a = xs[(r0 + i) * 128 + kk];
                acc[i][0] += a * w.x;
                acc[i][1] += a * w.y;
                acc[i][2] += a * w.z;
                acc[i][3] += a * w.w;
            }
        }
    }

    float4 bb = *(const float4*)(b1 + c0);
    #pragma unroll
    for (int i = 0; i < 4; ++i) {
        float o0 = acc[i][0] + bb.x; o0 = o0 > 0.f ? o0 : 0.f;
        float o1 = acc[i][1] + bb.y; o1 = o1 > 0.f ? o1 : 0.f;
        float o2 = acc[i][2] + bb.z; o2 = o2 > 0.f ? o2 : 0.f;
        float o3 = acc[i][3] + bb.w; o3 = o3 > 0.f ? o3 : 0.f;
        float s = o0 + o1 + o2 + o3;
        #pragma unroll
        for (int m = 16; m >= 1; m >>= 1) s += __shfl_xor(s, m);
        float mean = s * (1.0f / 128.0f);
        float d0 = o0 - mean, d1 = o1 - mean, d2 = o2 - mean, d3 = o3 - mean;
        float q = d0 * d0 + d1 * d1 + d2 * d2 + d3 * d3;
        #pragma unroll
        for (int m = 16; m >= 1; m >>= 1) q += __shfl_xor(q, m);
        float inv = 0.f;
        if (q > 0.f) inv = 1.0f / sqrtf(q * (1.0f / 127.0f));
        int row = r0 + i;
        if (row < rows_this) {
            float z0 = d0 * inv, z1 = d1 * inv, z2 = d2 * inv, z3 = d3 * inv;
            uint2 pk;
            pk.x = (unsigned)f2bf(z0) | ((unsigned)f2bf(z1) << 16);
            pk.y = (unsigned)f2bf(z2) | ((unsigned)f2bf(z3) << 16);
            *(uint2*)(xbf + (row0 + row) * 128 + c0) = pk;
            *(unsigned*)(x8 + (row0 + row) * 128 + c0) = pk_fp8x4(z0, z1, z2, z3);
        }
    }
}

// ---------------- CSR build (unified, N rows, global cols) ----------------
__global__ __launch_bounds__(256) void count_rows(const int* __restrict__ rows, int E,
                                                  int* __restrict__ cnt) {
    int i = (blockIdx.x * 256 + threadIdx.x) * 4;
    if (i + 4 <= E) {
        int4 r = *(const int4*)(rows + i);
        atomicAdd(&cnt[r.x], 1);
        atomicAdd(&cnt[r.y], 1);
        atomicAdd(&cnt[r.z], 1);
        atomicAdd(&cnt[r.w], 1);
    } else {
        for (; i < E; ++i) atomicAdd(&cnt[rows[i]], 1);
    }
}

__global__ __launch_bounds__(256) void scan1(const int* __restrict__ cnt, int R,
                                             int* __restrict__ rp, int* __restrict__ bt) {
    __shared__ int lds[256];
    int t = threadIdx.x, b = blockIdx.x;
    int base = b * 4096 + t * 16;
    int v[16];
    int s = 0;
    #pragma unroll
    for (int i = 0; i < 16; ++i) {
        int idx = base + i;
        int c = (idx < R) ? cnt[idx] : 0;
        v[i] = s;
        s += c;
    }
    lds[t] = s;
    __syncthreads();
    for (int off = 1; off < 256; off <<= 1) {
        int x = (t >= off) ? lds[t - off] : 0;
        __syncthreads();
        lds[t] += x;
        __syncthreads();
    }
    int excl = lds[t] - s;
    #pragma unroll
    for (int i = 0; i < 16; ++i) {
        int idx = base + i;
        if (idx < R) rp[idx] = excl + v[i];
    }
    if (t == 0) bt[b] = lds[255];
}

__global__ __launch_bounds__(64) void scan2(const int* __restrict__ bt, int B,
                                            int* __restrict__ bo, int* __restrict__ rp,
                                            int R, int E2) {
    int t = threadIdx.x;
    int v = (t < B) ? bt[t] : 0;
    int inc = v;
    #pragma unroll
    for (int off = 1; off < 64; off <<= 1) {
        int y = __shfl_up(inc, off);
        if (t >= off) inc += y;
    }
    if (t < B) bo[t] = inc - v;
    if (t == 0) rp[R] = E2;
}

__global__ __launch_bounds__(256) void scan3(int* __restrict__ rp, const int* __restrict__ bo,
                                             int* __restrict__ woff, int R) {
    int i = blockIdx.x * 256 + threadIdx.x;
    if (i < R) {
        int val = rp[i] + bo[i >> 12];
        rp[i] = val;
        woff[i] = val;
    }
}

__global__ __launch_bounds__(256) void binit(const int* __restrict__ rp, int NR,
                                             int nbuck, int* __restrict__ bcur) {
    int b = blockIdx.x * 256 + threadIdx.x;
    if (b < nbuck) {
        int r = b << 9;
        if (r > NR) r = NR;
        bcur[b] = rp[r];
    }
}

// ---- phase 1: partition edges into 512-row buckets (L2-local writes) ----
__global__ __launch_bounds__(256) void partition_edges(const int* __restrict__ rows,
                                                       const int* __restrict__ cols,
                                                       const float* __restrict__ vals,
                                                       int E, int nbuck,
                                                       int* __restrict__ bcur,
                                                       int2* __restrict__ tmp) {
    __shared__ int hist[512];
    __shared__ int gbase[512];
    __shared__ int cnt2[512];
    int t = threadIdx.x;
    for (int b = t; b < nbuck; b += 256) { hist[b] = 0; cnt2[b] = 0; }
    __syncthreads();
    long base = (long)blockIdx.x * 4096;
    #pragma unroll
    for (int k = 0; k < 16; ++k) {
        long i = base + k * 256 + t;
        if (i < E) atomicAdd(&hist[rows[i] >> 9], 1);
    }
    __syncthreads();
    for (int b = t; b < nbuck; b += 256) {
        int h = hist[b];
        gbase[b] = h ? atomicAdd(&bcur[b], h) : 0;
    }
    __syncthreads();
    #pragma unroll
    for (int k = 0; k < 16; ++k) {
        long i = base + k * 256 + t;
        if (i < E) {
            int rl = rows[i];
            int b = rl >> 9;
            int rank = atomicAdd(&cnt2[b], 1);
            int2 rec;
            rec.x = ((rl - (b << 9)) << 18) | cols[i];
            rec.y = __float_as_int(vals[i]);
            tmp[gbase[b] + rank] = rec;
        }
    }
}

// ---- phase 2: exact-position scatter within one bucket ----
// 8 blocks per bucket (contiguous chunks), x4 unrolled independent chains
#define PSPLIT 8
__global__ __launch_bounds__(256) void place_edges(const int* __restrict__ rp,
                                                   const int2* __restrict__ tmp,
                                                   int NR,
                                                   int* __restrict__ woff,
                                                   int2* __restrict__ scv) {
    int b = blockIdx.x >> 3;
    int s = blockIdx.x & (PSPLIT - 1);
    int srow = b << 9;
    int erow = srow + 512;
    if (erow > NR) erow = NR;
    int start = rp[srow], endp = rp[erow];
    int len = endp - start;
    int chunk = (len + PSPLIT - 1) / PSPLIT;
    int cbeg = start + s * chunk;
    int cend = cbeg + chunk;
    if (cend > endp) cend = endp;

    int i = cbeg + threadIdx.x;
    for (; i + 768 < cend; i += 1024) {
        int2 a0 = tmp[i];
        int2 a1 = tmp[i + 256];
        int2 a2 = tmp[i + 512];
        int2 a3 = tmp[i + 768];
        int r0 = srow + (a0.x >> 18);
        int r1 = srow + (a1.x >> 18);
        int r2 = srow + (a2.x >> 18);
        int r3 = srow + (a3.x >> 18);
        int p0 = atomicAdd(&woff[r0], 1);
        int p1 = atomicAdd(&woff[r1], 1);
        int p2 = atomicAdd(&woff[r2], 1);
        int p3 = atomicAdd(&woff[r3], 1);
        int2 o0; o0.x = a0.x & 0x3ffff; o0.y = a0.y;
        int2 o1; o1.x = a1.x & 0x3ffff; o1.y = a1.y;
        int2 o2; o2.x = a2.x & 0x3ffff; o2.y = a2.y;
        int2 o3; o3.x = a3.x & 0x3ffff; o3.y = a3.y;
        scv[p0] = o0;
        scv[p1] = o1;
        scv[p2] = o2;
        scv[p3] = o3;
    }
    for (; i < cend; i += 256) {
        int2 rec = tmp[i];
        int row = srow + (rec.x >> 18);
        int p = atomicAdd(&woff[row], 1);
        int2 o;
        o.x = rec.x & 0x3ffff;
        o.y = rec.y;
        scv[p] = o;
    }
}

// decode one fp8 row-segment (8 vals in uint2) and packed-fma into acc[4]
#define DEC_FMA(qq, vv) do {                                                        \
    f32x2 vp_ = {(vv), (vv)};                                                       \
    acc[0] = __builtin_elementwise_fma(vp_, __builtin_amdgcn_cvt_pk_f32_fp8((qq).x, false), acc[0]); \
    acc[1] = __builtin_elementwise_fma(vp_, __builtin_amdgcn_cvt_pk_f32_fp8((qq).x, true),  acc[1]); \
    acc[2] = __builtin_elementwise_fma(vp_, __builtin_amdgcn_cvt_pk_f32_fp8((qq).y, false), acc[2]); \
    acc[3] = __builtin_elementwise_fma(vp_, __builtin_amdgcn_cvt_pk_f32_fp8((qq).y, true),  acc[3]); \
} while (0)

// ---- SpMM core: one row per 16-lane quarter, unroll x8, fp8 gathers ----
__device__ inline void spmm_core8(const int* __restrict__ rp,
                                  const int2* __restrict__ scv,
                                  const unsigned char* __restrict__ g8,
                                  int row, int f, f32x2* acc) {
    int beg = rp[row], end = rp[row + 1];
    int j = beg;
    // align to even index so int4 (edge-pair) loads are 16B-aligned
    if ((j & 1) && j < end) {
        int2 r0 = scv[j];
        uint2 q0 = *(const uint2*)(g8 + ((long)r0.x << 7) + f);
        float v0 = __int_as_float(r0.y);
        DEC_FMA(q0, v0);
        ++j;
    }
    for (; j + 8 <= end; j += 8) {
        int4 s01 = *(const int4*)(scv + j);
        int4 s23 = *(const int4*)(scv + j + 2);
        int4 s45 = *(const int4*)(scv + j + 4);
        int4 s67 = *(const int4*)(scv + j + 6);
        uint2 q0 = *(const uint2*)(g8 + ((long)s01.x << 7) + f);
        uint2 q1 = *(const uint2*)(g8 + ((long)s01.z << 7) + f);
        uint2 q2 = *(const uint2*)(g8 + ((long)s23.x << 7) + f);
        uint2 q3 = *(const uint2*)(g8 + ((long)s23.z << 7) + f);
        uint2 q4 = *(const uint2*)(g8 + ((long)s45.x << 7) + f);
        uint2 q5 = *(const uint2*)(g8 + ((long)s45.z << 7) + f);
        uint2 q6 = *(const uint2*)(g8 + ((long)s67.x << 7) + f);
        uint2 q7 = *(const uint2*)(g8 + ((long)s67.z << 7) + f);
        DEC_FMA(q0, __int_as_float(s01.y));
        DEC_FMA(q1, __int_as_float(s01.w));
        DEC_FMA(q2, __int_as_float(s23.y));
        DEC_FMA(q3, __int_as_float(s23.w));
        DEC_FMA(q4, __int_as_float(s45.y));
        DEC_FMA(q5, __int_as_float(s45.w));
        DEC_FMA(q6, __int_as_float(s67.y));
        DEC_FMA(q7, __int_as_float(s67.w));
    }
    for (; j + 2 <= end; j += 2) {
        int4 s01 = *(const int4*)(scv + j);
        uint2 q0 = *(const uint2*)(g8 + ((long)s01.x << 7) + f);
        uint2 q1 = *(const uint2*)(g8 + ((long)s01.z << 7) + f);
        DEC_FMA(q0, __int_as_float(s01.y));
        DEC_FMA(q1, __int_as_float(s01.w));
    }
    if (j < end) {
        int2 r0 = scv[j];
        uint2 q0 = *(const uint2*)(g8 + ((long)r0.x << 7) + f);
        float v0 = __int_as_float(r0.y);
        DEC_FMA(q0, v0);
    }
}

// h = M @ X : gathers X8 (fp8), writes h as bf16 (stream copy) + fp8 (gather copy)
__global__ __launch_bounds__(256) void spmm_plain(const int* __restrict__ rp,
                                                  const int2* __restrict__ scv,
                                                  const unsigned char* __restrict__ x8,
                                                  unsigned short* __restrict__ houtbf,
                                                  unsigned char* __restrict__ hout8,
                                                  int R) {
    int wave = blockIdx.x * 4 + (threadIdx.x >> 6);
    int lane = threadIdx.x & 63;
    int row = wave * 4 + (lane >> 4);
    if (row >= R) return;
    int f = (lane & 15) << 3;
    f32x2 acc[4];
    #pragma unroll
    for (int i = 0; i < 4; ++i) acc[i] = (f32x2){0.f, 0.f};
    spmm_core8(rp, scv, x8, row, f, acc);
    uint4 o;
    o.x = (unsigned)f2bf(acc[0].x) | ((unsigned)f2bf(acc[0].y) << 16);
    o.y = (unsigned)f2bf(acc[1].x) | ((unsigned)f2bf(acc[1].y) << 16);
    o.z = (unsigned)f2bf(acc[2].x) | ((unsigned)f2bf(acc[2].y) << 16);
    o.w = (unsigned)f2bf(acc[3].x) | ((unsigned)f2bf(acc[3].y) << 16);
    *(uint4*)(houtbf + ((long)row << 7) + f) = o;
    uint2 o8;
    o8.x = pk_fp8x4(acc[0].x, acc[0].y, acc[1].x, acc[1].y);
    o8.y = pk_fp8x4(acc[2].x, acc[2].y, acc[3].x, acc[3].y);
    *(uint2*)(hout8 + ((long)row << 7) + f) = o8;
}

// pass-1 update: X = c0*X + c_h[seg]*h + c_2nd[seg]*(M @ h)
// gathers h8 (fp8); streams Xbf,hbf (bf16); writes Xbf (bf16) + X8 (fp8)
__global__ __launch_bounds__(256) void spmm_update(const int* __restrict__ rp,
                                                   const int2* __restrict__ scv,
                                                   const unsigned char* __restrict__ h8,
                                                   const unsigned short* __restrict__ hbf,
                                                   unsigned short* __restrict__ Xbf,
                                                   unsigned char* __restrict__ X8,
                                                   const float* __restrict__ coe,
                                                   int ihA, int iaA, int ihP, int iaP,
                                                   int NA, int R) {
    int wave = blockIdx.x * 4 + (threadIdx.x >> 6);
    int lane = threadIdx.x & 63;
    int row = wave * 4 + (lane >> 4);
    if (row >= R) return;
    int f = (lane & 15) << 3;
    f32x2 acc[4];
    #pragma unroll
    for (int i = 0; i < 4; ++i) acc[i] = (f32x2){0.f, 0.f};
    spmm_core8(rp, scv, h8, row, f, acc);

    float c0 = coe[0];
    float ch = coe[row < NA ? ihA : ihP];
    float ca = coe[row < NA ? iaA : iaP];
    long o = ((long)row << 7) + f;
    uint4 xv = *(const uint4*)(Xbf + o);
    uint4 hs = *(const uint4*)(hbf + o);
    float r[8];
    r[0] = c0 * bflo(xv.x) + ch * bflo(hs.x) + ca * acc[0].x;
    r[1] = c0 * bfhi(xv.x) + ch * bfhi(hs.x) + ca * acc[0].y;
    r[2] = c0 * bflo(xv.y) + ch * bflo(hs.y) + ca * acc[1].x;
    r[3] = c0 * bfhi(xv.y) + ch * bfhi(hs.y) + ca * acc[1].y;
    r[4] = c0 * bflo(xv.z) + ch * bflo(hs.z) + ca * acc[2].x;
    r[5] = c0 * bfhi(xv.z) + ch * bfhi(hs.z) + ca * acc[2].y;
    r[6] = c0 * bflo(xv.w) + ch * bflo(hs.w) + ca * acc[3].x;
    r[7] = c0 * bfhi(xv.w) + ch * bfhi(hs.w) + ca * acc[3].y;
    uint4 ob;
    ob.x = (unsigned)f2bf(r[0]) | ((unsigned)f2bf(r[1]) << 16);
    ob.y = (unsigned)f2bf(r[2]) | ((unsigned)f2bf(r[3]) << 16);
    ob.z = (unsigned)f2bf(r[4]) | ((unsigned)f2bf(r[5]) << 16);
    ob.w = (unsigned)f2bf(r[6]) | ((unsigned)f2bf(r[7]) << 16);
    *(uint4*)(Xbf + o) = ob;
    uint2 o8;
    o8.x = pk_fp8x4(r[0], r[1], r[2], r[3]);
    o8.y = pk_fp8x4(r[4], r[5], r[6], r[7]);
    *(uint2*)(X8 + o) = o8;
}

// pass-2 update fused with final GEMM:
//   res2(fp32) = c0*Xbf + c_h[seg]*hbf + c_2nd[seg]*(M @ h8)  -> LDS
//   out[row] = res2[row] @ W2 + b2     (res2 never hits HBM)
__global__ __launch_bounds__(256) void spmm_update_out(const int* __restrict__ rp,
                                                       const int2* __restrict__ scv,
                                                       const unsigned char* __restrict__ h8,
                                                       const unsigned short* __restrict__ hbf,
                                                       const unsigned short* __restrict__ Xbf,
                                                       const float* __restrict__ coe,
                                                       const float* __restrict__ W2,
                                                       const float* __restrict__ b2,
                                                       float* __restrict__ out,
                                                       int ihA, int iaA, int ihP, int iaP,
                                                       int NA, int R) {
    __shared__ float xs[16 * 132];
    __shared__ float wT[16 * 132];   // wT[c][k] = W2[k][c]
    __shared__ float bs[16];
    int t = threadIdx.x;
    #pragma unroll
    for (int i = 0; i < 8; ++i) {
        int idx = i * 256 + t;                // 2048 = 128*16
        wT[(idx & 15) * 132 + (idx >> 4)] = W2[idx];
    }
    if (t < 16) bs[t] = b2[t];

    int lane = t & 63;
    int rl = (t >> 6) * 4 + (lane >> 4);
    int row = blockIdx.x * 16 + rl;
    int f = (lane & 15) << 3;
    if (row < R) {
        f32x2 acc[4];
        #pragma unroll
        for (int i = 0; i < 4; ++i) acc[i] = (f32x2){0.f, 0.f};
        spmm_core8(rp, scv, h8, row, f, acc);
        float c0 = coe[0];
        float ch = coe[row < NA ? ihA : ihP];
        float ca = coe[row < NA ? iaA : iaP];
        long o = ((long)row << 7) + f;
        uint4 xv = *(const uint4*)(Xbf + o);
        uint4 hs = *(const uint4*)(hbf + o);
        float* x = &xs[rl * 132 + f];
        x[0] = c0 * bflo(xv.x) + ch * bflo(hs.x) + ca * acc[0].x;
        x[1] = c0 * bfhi(xv.x) + ch * bfhi(hs.x) + ca * acc[0].y;
        x[2] = c0 * bflo(xv.y) + ch * bflo(hs.y) + ca * acc[1].x;
        x[3] = c0 * bfhi(xv.y) + ch * bfhi(hs.y) + ca * acc[1].y;
        x[4] = c0 * bflo(xv.z) + ch * bflo(hs.z) + ca * acc[2].x;
        x[5] = c0 * bfhi(xv.z) + ch * bfhi(hs.z) + ca * acc[2].y;
        x[6] = c0 * bflo(xv.w) + ch * bflo(hs.w) + ca * acc[3].x;
        x[7] = c0 * bfhi(xv.w) + ch * bfhi(hs.w) + ca * acc[3].y;
    }
    __syncthreads();
    int orl = t >> 4, c = t & 15;
    long orow = (long)blockIdx.x * 16 + orl;
    if (orow < R) {
        const float* xrow = &xs[orl * 132];
        const float* wrow = &wT[c * 132];
        f32x4 a4 = {0.f, 0.f, 0.f, 0.f};
        #pragma unroll 8
        for (int k = 0; k < 128; k += 4) {
            f32x4 xv = *(const f32x4*)(xrow + k);
            f32x4 wv = *(const f32x4*)(wrow + k);
            a4 = __builtin_elementwise_fma(xv, wv, a4);
        }
        out[orow * 16 + c] = a4.x + a4.y + a4.z + a4.w + bs[c];
    }
}

extern "C" void kernel_launch(void* const* d_in, const int* in_sizes, int n_in,
                              void* d_out, int out_size, void* d_ws, size_t ws_size,
                              hipStream_t stream) {
    const float* x0  = (const float*)d_in[0];
    const float* x1  = (const float*)d_in[1];
    const float* vap = (const float*)d_in[2];
    const float* vpa = (const float*)d_in[3];
    const int*   rap = (const int*)d_in[4];
    const int*   cap = (const int*)d_in[5];
    const int*   rpa = (const int*)d_in[6];
    const int*   cpa = (const int*)d_in[7];
    const float* Wp0 = (const float*)d_in[8];
    const float* Wp1 = (const float*)d_in[9];
    const float* W1  = (const float*)d_in[10];
    const float* b1  = (const float*)d_in[11];
    const float* W2  = (const float*)d_in[12];
    const float* b2  = (const float*)d_in[13];
    const float* coe = (const float*)d_in[14];
    float* out = (float*)d_out;

    const int NA = in_sizes[0] / 128;
    const int NP = in_sizes[1] / 128;
    const int N  = NA + NP;
    const int E  = in_sizes[2];
    const int E2 = 2 * E;

    char* p = (char*)d_ws;
    auto alloc = [&](size_t bytes) {
        char* r = p;
        p += (bytes + 255) & ~(size_t)255;
        return r;
    };
    unsigned short* Xbf = (unsigned short*)alloc((size_t)N * 128 * 2);
    unsigned short* hbf = (unsigned short*)alloc((size_t)N * 128 * 2);
    unsigned char* X8 = (unsigned char*)alloc((size_t)N * 128);
    unsigned char* h8 = (unsigned char*)alloc((size_t)N * 128);
    float* M0  = (float*)alloc(128 * 128 * 4);
    float* M1  = (float*)alloc(128 * 128 * 4);
    int* cnt   = (int*)alloc((size_t)N * 4);
    int* rp    = (int*)alloc((size_t)(N + 1) * 4);
    int* woff  = (int*)alloc((size_t)N * 4);
    int* bt    = (int*)alloc(64 * 4);
    int* bo    = (int*)alloc(64 * 4);
    int2* scv  = (int2*)alloc((size_t)E2 * 8);
    int* bcur  = (int*)alloc(512 * 4);
    if ((size_t)(p - (char*)d_ws) > ws_size) return;

    // tmp partition buffer aliases Xbf (Xbf written only after CSR build);
    // E2*8 = 32 MB <= N*256B = 64 MB
    int2* tmp = (int2*)Xbf;

    const int eg = (E + 255) / 256;
    const int nbuck = (N + 511) >> 9;
    const int pg = (E + 4095) / 4096;

    // ---- unified CSR build ----
    hipMemsetAsync(cnt, 0, (size_t)N * 4, stream);
    const int cg = (E / 4 + 255) / 256;
    count_rows<<<cg, 256, 0, stream>>>(rap, E, cnt);
    count_rows<<<cg, 256, 0, stream>>>(rpa, E, cnt);
    int B = (N + 4095) / 4096;
    scan1<<<B, 256, 0, stream>>>(cnt, N, rp, bt);
    scan2<<<1, 64, 0, stream>>>(bt, B, bo, rp, N, E2);
    scan3<<<(N + 255) / 256, 256, 0, stream>>>(rp, bo, woff, N);
    binit<<<2, 256, 0, stream>>>(rp, N, nbuck, bcur);
    partition_edges<<<pg, 256, 0, stream>>>(rap, cap, vap, E, nbuck, bcur, tmp);
    partition_edges<<<pg, 256, 0, stream>>>(rpa, cpa, vpa, E, nbuck, bcur, tmp);
    place_edges<<<nbuck * PSPLIT, 256, 0, stream>>>(rp, tmp, N, woff, scv);

    // ---- dense front-end (Xbf written AFTER tmp aliasing done) ----
    fuse_w<<<256, 128, 0, stream>>>(Wp0, Wp1, W1, M0, M1);
    gemm_relu_norm<<<(NA + 31) / 32, 256, 0, stream>>>(x0, M0, b1, Xbf, X8, NA);
    gemm_relu_norm<<<(NP + 31) / 32, 256, 0, stream>>>(
        x1, M1, b1, Xbf + (size_t)NA * 128, X8 + (size_t)NA * 128, NP);

    const int sg = (N + 15) / 16;

    // ---- pass 1 (AP first): A rows coe1/coe3, P rows coe2/coe4 ----
    spmm_plain<<<sg, 256, 0, stream>>>(rp, scv, X8, hbf, h8, N);
    spmm_update<<<sg, 256, 0, stream>>>(rp, scv, h8, hbf, Xbf, X8, coe, 1, 3, 2, 4, NA, N);

    // ---- pass 2 (PA first) fused with out = res2 @ W2 + b2 ----
    spmm_plain<<<sg, 256, 0, stream>>>(rp, scv, X8, hbf, h8, N);
    spmm_update_out<<<sg, 256, 0, stream>>>(rp, scv, h8, hbf, Xbf, coe,
                                            W2, b2, out, 2, 4, 1, 3, NA, N);
}

// Round 5
// 998.822 us; speedup vs baseline: 1.0930x; 1.0930x over previous
//
#include <hip/hip_runtime.h>
#include <hip/hip_bf16.h>

// PSHGCN on MI355X — round 10 (= round 9 resubmit; container infra failure):
//  * place_edges rebuilt with ZERO global atomics. Round-8 post-mortem:
//    WRITE_SIZE 204 MB >> 32 MB payload — the 4M global atomicAdd-with-return
//    ops were generating memory-side RMW traffic at ~1.5 TB/s = the limiter
//    (occupancy fix was a no-op because it was never latency-bound).
//    New scheme: 1 block (1024 thr) per 512-row bucket; LDS histogram ->
//    LDS prefix-sum -> LDS-atomic rank scatter to exact CSR slots.
//    tmp re-read hits L2 (65 KB/bucket). woff buffer deleted.
//  * everything else unchanged from round 8.

typedef float f32x2 __attribute__((ext_vector_type(2)));
typedef float f32x4 __attribute__((ext_vector_type(4)));

__device__ inline unsigned short f2bf(float x) {
    unsigned b = __float_as_uint(x);
    unsigned r = (b + 0x7fffu + ((b >> 16) & 1u)) >> 16;
    return (unsigned short)r;
}
__device__ inline float bflo(unsigned u) { return __uint_as_float(u << 16); }
__device__ inline float bfhi(unsigned u) { return __uint_as_float(u & 0xffff0000u); }

// pack 4 floats -> 4 fp8 e4m3 bytes (a in byte0 .. d in byte3)
__device__ inline unsigned pk_fp8x4(float a, float b, float c, float d) {
    int v = __builtin_amdgcn_cvt_pk_fp8_f32(a, b, 0, false);
    v = __builtin_amdgcn_cvt_pk_fp8_f32(c, d, v, true);
    return (unsigned)v;
}

// ---------------- dense: M = Wp @ W1 (two 128x128x128) ----------------
__global__ __launch_bounds__(128) void fuse_w(const float* __restrict__ Wp0,
                                              const float* __restrict__ Wp1,
                                              const float* __restrict__ W1,
                                              float* __restrict__ M0,
                                              float* __restrict__ M1) {
    int m = blockIdx.x >> 7;
    int i = blockIdx.x & 127;
    const float* Wp = m ? Wp1 : Wp0;
    float* M = m ? M1 : M0;
    __shared__ float r[128];
    int t = threadIdx.x;
    r[t] = Wp[i * 128 + t];
    __syncthreads();
    float acc = 0.f;
    #pragma unroll 8
    for (int k = 0; k < 128; ++k) acc += r[k] * W1[k * 128 + t];
    M[i * 128 + t] = acc;
}

// ---- dense: Xbf/X8 = normalize(relu(xin @ M + b1))  (bf16 + fp8 out) ----
__global__ __launch_bounds__(256) void gemm_relu_norm(const float* __restrict__ xin,
                                                      const float* __restrict__ M,
                                                      const float* __restrict__ b1,
                                                      unsigned short* __restrict__ xbf,
                                                      unsigned char* __restrict__ x8,
                                                      int nrows) {
    __shared__ float Wl[64 * 128];
    __shared__ float xs[32 * 128];
    int t = threadIdx.x;
    long row0 = (long)blockIdx.x * 32;
    int rows_this = nrows - (int)row0;
    if (rows_this > 32) rows_this = 32;

    #pragma unroll
    for (int it = 0; it < 4; ++it) {
        int g4 = it * 256 + t;
        int g = g4 * 4;
        int rl = g >> 7, c = g & 127;
        float4 val = {0.f, 0.f, 0.f, 0.f};
        if (rl < rows_this) val = *(const float4*)(xin + (row0 + rl) * 128 + c);
        *(float4*)&xs[rl * 128 + c] = val;
    }

    int r0 = (t >> 5) * 4;
    int c0 = (t & 31) * 4;
    float acc[4][4];
    #pragma unroll
    for (int i = 0; i < 4; ++i)
        #pragma unroll
        for (int j = 0; j < 4; ++j) acc[i][j] = 0.f;

    for (int h = 0; h < 2; ++h) {
        __syncthreads();
        #pragma unroll
        for (int it = 0; it < 8; ++it) {
            int g4 = it * 256 + t;
            ((float4*)Wl)[g4] = ((const float4*)(M + h * 8192))[g4];
        }
        __syncthreads();
        #pragma unroll 4
        for (int k = 0; k < 64; ++k) {
            float4 w = *(float4*)&Wl[k * 128 + c0];
            int kk = h * 64 + k;
            #pragma unroll
            for (int i = 0; i < 4; ++i) {
                float a = xs[(r0 + i) * 128 + kk];
                acc[i][0] += a * w.x;
                acc[i][1] += a * w.y;
                acc[i][2] += a * w.z;
                acc[i][3] += a * w.w;
            }
        }
    }

    float4 bb = *(const float4*)(b1 + c0);
    #pragma unroll
    for (int i = 0; i < 4; ++i) {
        float o0 = acc[i][0] + bb.x; o0 = o0 > 0.f ? o0 : 0.f;
        float o1 = acc[i][1] + bb.y; o1 = o1 > 0.f ? o1 : 0.f;
        float o2 = acc[i][2] + bb.z; o2 = o2 > 0.f ? o2 : 0.f;
        float o3 = acc[i][3] + bb.w; o3 = o3 > 0.f ? o3 : 0.f;
        float s = o0 + o1 + o2 + o3;
        #pragma unroll
        for (int m = 16; m >= 1; m >>= 1) s += __shfl_xor(s, m);
        float mean = s * (1.0f / 128.0f);
        float d0 = o0 - mean, d1 = o1 - mean, d2 = o2 - mean, d3 = o3 - mean;
        float q = d0 * d0 + d1 * d1 + d2 * d2 + d3 * d3;
        #pragma unroll
        for (int m = 16; m >= 1; m >>= 1) q += __shfl_xor(q, m);
        float inv = 0.f;
        if (q > 0.f) inv = 1.0f / sqrtf(q * (1.0f / 127.0f));
        int row = r0 + i;
        if (row < rows_this) {
            float z0 = d0 * inv, z1 = d1 * inv, z2 = d2 * inv, z3 = d3 * inv;
            uint2 pk;
            pk.x = (unsigned)f2bf(z0) | ((unsigned)f2bf(z1) << 16);
            pk.y = (unsigned)f2bf(z2) | ((unsigned)f2bf(z3) << 16);
            *(uint2*)(xbf + (row0 + row) * 128 + c0) = pk;
            *(unsigned*)(x8 + (row0 + row) * 128 + c0) = pk_fp8x4(z0, z1, z2, z3);
        }
    }
}

// ---------------- CSR build (unified, N rows, global cols) ----------------
__global__ __launch_bounds__(256) void count_rows(const int* __restrict__ rows, int E,
                                                  int* __restrict__ cnt) {
    int i = (blockIdx.x * 256 + threadIdx.x) * 4;
    if (i + 4 <= E) {
        int4 r = *(const int4*)(rows + i);
        atomicAdd(&cnt[r.x], 1);
        atomicAdd(&cnt[r.y], 1);
        atomicAdd(&cnt[r.z], 1);
        atomicAdd(&cnt[r.w], 1);
    } else {
        for (; i < E; ++i) atomicAdd(&cnt[rows[i]], 1);
    }
}

__global__ __launch_bounds__(256) void scan1(const int* __restrict__ cnt, int R,
                                             int* __restrict__ rp, int* __restrict__ bt) {
    __shared__ int lds[256];
    int t = threadIdx.x, b = blockIdx.x;
    int base = b * 4096 + t * 16;
    int v[16];
    int s = 0;
    #pragma unroll
    for (int i = 0; i < 16; ++i) {
        int idx = base + i;
        int c = (idx < R) ? cnt[idx] : 0;
        v[i] = s;
        s += c;
    }
    lds[t] = s;
    __syncthreads();
    for (int off = 1; off < 256; off <<= 1) {
        int x = (t >= off) ? lds[t - off] : 0;
        __syncthreads();
        lds[t] += x;
        __syncthreads();
    }
    int excl = lds[t] - s;
    #pragma unroll
    for (int i = 0; i < 16; ++i) {
        int idx = base + i;
        if (idx < R) rp[idx] = excl + v[i];
    }
    if (t == 0) bt[b] = lds[255];
}

__global__ __launch_bounds__(64) void scan2(const int* __restrict__ bt, int B,
                                            int* __restrict__ bo, int* __restrict__ rp,
                                            int R, int E2) {
    int t = threadIdx.x;
    int v = (t < B) ? bt[t] : 0;
    int inc = v;
    #pragma unroll
    for (int off = 1; off < 64; off <<= 1) {
        int y = __shfl_up(inc, off);
        if (t >= off) inc += y;
    }
    if (t < B) bo[t] = inc - v;
    if (t == 0) rp[R] = E2;
}

__global__ __launch_bounds__(256) void scan3(int* __restrict__ rp, const int* __restrict__ bo,
                                             int R) {
    int i = blockIdx.x * 256 + threadIdx.x;
    if (i < R) rp[i] = rp[i] + bo[i >> 12];
}

__global__ __launch_bounds__(256) void binit(const int* __restrict__ rp, int NR,
                                             int nbuck, int* __restrict__ bcur) {
    int b = blockIdx.x * 256 + threadIdx.x;
    if (b < nbuck) {
        int r = b << 9;
        if (r > NR) r = NR;
        bcur[b] = rp[r];
    }
}

// ---- phase 1: partition edges into 512-row buckets (L2-local writes) ----
__global__ __launch_bounds__(256) void partition_edges(const int* __restrict__ rows,
                                                       const int* __restrict__ cols,
                                                       const float* __restrict__ vals,
                                                       int E, int nbuck,
                                                       int* __restrict__ bcur,
                                                       int2* __restrict__ tmp) {
    __shared__ int hist[512];
    __shared__ int gbase[512];
    __shared__ int cnt2[512];
    int t = threadIdx.x;
    for (int b = t; b < nbuck; b += 256) { hist[b] = 0; cnt2[b] = 0; }
    __syncthreads();
    long base = (long)blockIdx.x * 4096;
    #pragma unroll
    for (int k = 0; k < 16; ++k) {
        long i = base + k * 256 + t;
        if (i < E) atomicAdd(&hist[rows[i] >> 9], 1);
    }
    __syncthreads();
    for (int b = t; b < nbuck; b += 256) {
        int h = hist[b];
        gbase[b] = h ? atomicAdd(&bcur[b], h) : 0;
    }
    __syncthreads();
    #pragma unroll
    for (int k = 0; k < 16; ++k) {
        long i = base + k * 256 + t;
        if (i < E) {
            int rl = rows[i];
            int b = rl >> 9;
            int rank = atomicAdd(&cnt2[b], 1);
            int2 rec;
            rec.x = ((rl - (b << 9)) << 18) | cols[i];
            rec.y = __float_as_int(vals[i]);
            tmp[gbase[b] + rank] = rec;
        }
    }
}

// ---- phase 2: exact-position scatter within one bucket, LDS atomics only ----
__global__ __launch_bounds__(1024) void place_edges(const int* __restrict__ rp,
                                                    const int2* __restrict__ tmp,
                                                    int NR,
                                                    int2* __restrict__ scv) {
    __shared__ int hist[512];
    __shared__ int hoff[512];
    int b = blockIdx.x;
    int srow = b << 9;
    int erow = srow + 512;
    if (erow > NR) erow = NR;
    int start = rp[srow], endp = rp[erow];
    int t = threadIdx.x;
    if (t < 512) hist[t] = 0;
    __syncthreads();

    // pass 1: per-row histogram in LDS
    for (int i = start + t; i < endp; i += 1024)
        atomicAdd(&hist[tmp[i].x >> 18], 1);
    __syncthreads();

    // prefix-sum (Hillis-Steele, inclusive) over 512 counters
    if (t < 512) hoff[t] = hist[t];
    __syncthreads();
    for (int off = 1; off < 512; off <<= 1) {
        int v = 0;
        if (t < 512 && t >= off) v = hoff[t - off];
        __syncthreads();
        if (t < 512) hoff[t] += v;
        __syncthreads();
    }
    // convert to running cursor = global base + exclusive prefix
    if (t < 512) hoff[t] = start + hoff[t] - hist[t];
    __syncthreads();

    // pass 2: rank via LDS atomic, scatter to exact CSR slot (tmp is L2-hot)
    int i = start + t;
    for (; i + 3 * 1024 < endp; i += 4 * 1024) {
        int2 a0 = tmp[i];
        int2 a1 = tmp[i + 1024];
        int2 a2 = tmp[i + 2048];
        int2 a3 = tmp[i + 3072];
        int p0 = atomicAdd(&hoff[a0.x >> 18], 1);
        int p1 = atomicAdd(&hoff[a1.x >> 18], 1);
        int p2 = atomicAdd(&hoff[a2.x >> 18], 1);
        int p3 = atomicAdd(&hoff[a3.x >> 18], 1);
        int2 o0; o0.x = a0.x & 0x3ffff; o0.y = a0.y;
        int2 o1; o1.x = a1.x & 0x3ffff; o1.y = a1.y;
        int2 o2; o2.x = a2.x & 0x3ffff; o2.y = a2.y;
        int2 o3; o3.x = a3.x & 0x3ffff; o3.y = a3.y;
        scv[p0] = o0;
        scv[p1] = o1;
        scv[p2] = o2;
        scv[p3] = o3;
    }
    for (; i < endp; i += 1024) {
        int2 rec = tmp[i];
        int p = atomicAdd(&hoff[rec.x >> 18], 1);
        int2 o;
        o.x = rec.x & 0x3ffff;
        o.y = rec.y;
        scv[p] = o;
    }
}

// decode one fp8 row-segment (8 vals in uint2) and packed-fma into acc[4]
#define DEC_FMA(qq, vv) do {                                                        \
    f32x2 vp_ = {(vv), (vv)};                                                       \
    acc[0] = __builtin_elementwise_fma(vp_, __builtin_amdgcn_cvt_pk_f32_fp8((qq).x, false), acc[0]); \
    acc[1] = __builtin_elementwise_fma(vp_, __builtin_amdgcn_cvt_pk_f32_fp8((qq).x, true),  acc[1]); \
    acc[2] = __builtin_elementwise_fma(vp_, __builtin_amdgcn_cvt_pk_f32_fp8((qq).y, false), acc[2]); \
    acc[3] = __builtin_elementwise_fma(vp_, __builtin_amdgcn_cvt_pk_f32_fp8((qq).y, true),  acc[3]); \
} while (0)

// ---- SpMM core: one row per 16-lane quarter, unroll x8, fp8 gathers ----
__device__ inline void spmm_core8(const int* __restrict__ rp,
                                  const int2* __restrict__ scv,
                                  const unsigned char* __restrict__ g8,
                                  int row, int f, f32x2* acc) {
    int beg = rp[row], end = rp[row + 1];
    int j = beg;
    // align to even index so int4 (edge-pair) loads are 16B-aligned
    if ((j & 1) && j < end) {
        int2 r0 = scv[j];
        uint2 q0 = *(const uint2*)(g8 + ((long)r0.x << 7) + f);
        float v0 = __int_as_float(r0.y);
        DEC_FMA(q0, v0);
        ++j;
    }
    for (; j + 8 <= end; j += 8) {
        int4 s01 = *(const int4*)(scv + j);
        int4 s23 = *(const int4*)(scv + j + 2);
        int4 s45 = *(const int4*)(scv + j + 4);
        int4 s67 = *(const int4*)(scv + j + 6);
        uint2 q0 = *(const uint2*)(g8 + ((long)s01.x << 7) + f);
        uint2 q1 = *(const uint2*)(g8 + ((long)s01.z << 7) + f);
        uint2 q2 = *(const uint2*)(g8 + ((long)s23.x << 7) + f);
        uint2 q3 = *(const uint2*)(g8 + ((long)s23.z << 7) + f);
        uint2 q4 = *(const uint2*)(g8 + ((long)s45.x << 7) + f);
        uint2 q5 = *(const uint2*)(g8 + ((long)s45.z << 7) + f);
        uint2 q6 = *(const uint2*)(g8 + ((long)s67.x << 7) + f);
        uint2 q7 = *(const uint2*)(g8 + ((long)s67.z << 7) + f);
        DEC_FMA(q0, __int_as_float(s01.y));
        DEC_FMA(q1, __int_as_float(s01.w));
        DEC_FMA(q2, __int_as_float(s23.y));
        DEC_FMA(q3, __int_as_float(s23.w));
        DEC_FMA(q4, __int_as_float(s45.y));
        DEC_FMA(q5, __int_as_float(s45.w));
        DEC_FMA(q6, __int_as_float(s67.y));
        DEC_FMA(q7, __int_as_float(s67.w));
    }
    for (; j + 2 <= end; j += 2) {
        int4 s01 = *(const int4*)(scv + j);
        uint2 q0 = *(const uint2*)(g8 + ((long)s01.x << 7) + f);
        uint2 q1 = *(const uint2*)(g8 + ((long)s01.z << 7) + f);
        DEC_FMA(q0, __int_as_float(s01.y));
        DEC_FMA(q1, __int_as_float(s01.w));
    }
    if (j < end) {
        int2 r0 = scv[j];
        uint2 q0 = *(const uint2*)(g8 + ((long)r0.x << 7) + f);
        float v0 = __int_as_float(r0.y);
        DEC_FMA(q0, v0);
    }
}

// h = M @ X : gathers X8 (fp8), writes h as bf16 (stream copy) + fp8 (gather copy)
__global__ __launch_bounds__(256) void spmm_plain(const int* __restrict__ rp,
                                                  const int2* __restrict__ scv,
                                                  const unsigned char* __restrict__ x8,
                                                  unsigned short* __restrict__ houtbf,
                                                  unsigned char* __restrict__ hout8,
                                                  int R) {
    int wave = blockIdx.x * 4 + (threadIdx.x >> 6);
    int lane = threadIdx.x & 63;
    int row = wave * 4 + (lane >> 4);
    if (row >= R) return;
    int f = (lane & 15) << 3;
    f32x2 acc[4];
    #pragma unroll
    for (int i = 0; i < 4; ++i) acc[i] = (f32x2){0.f, 0.f};
    spmm_core8(rp, scv, x8, row, f, acc);
    uint4 o;
    o.x = (unsigned)f2bf(acc[0].x) | ((unsigned)f2bf(acc[0].y) << 16);
    o.y = (unsigned)f2bf(acc[1].x) | ((unsigned)f2bf(acc[1].y) << 16);
    o.z = (unsigned)f2bf(acc[2].x) | ((unsigned)f2bf(acc[2].y) << 16);
    o.w = (unsigned)f2bf(acc[3].x) | ((unsigned)f2bf(acc[3].y) << 16);
    *(uint4*)(houtbf + ((long)row << 7) + f) = o;
    uint2 o8;
    o8.x = pk_fp8x4(acc[0].x, acc[0].y, acc[1].x, acc[1].y);
    o8.y = pk_fp8x4(acc[2].x, acc[2].y, acc[3].x, acc[3].y);
    *(uint2*)(hout8 + ((long)row << 7) + f) = o8;
}

// pass-1 update: X = c0*X + c_h[seg]*h + c_2nd[seg]*(M @ h)
// gathers h8 (fp8); streams Xbf,hbf (bf16); writes Xbf (bf16) + X8 (fp8)
__global__ __launch_bounds__(256) void spmm_update(const int* __restrict__ rp,
                                                   const int2* __restrict__ scv,
                                                   const unsigned char* __restrict__ h8,
                                                   const unsigned short* __restrict__ hbf,
                                                   unsigned short* __restrict__ Xbf,
                                                   unsigned char* __restrict__ X8,
                                                   const float* __restrict__ coe,
                                                   int ihA, int iaA, int ihP, int iaP,
                                                   int NA, int R) {
    int wave = blockIdx.x * 4 + (threadIdx.x >> 6);
    int lane = threadIdx.x & 63;
    int row = wave * 4 + (lane >> 4);
    if (row >= R) return;
    int f = (lane & 15) << 3;
    f32x2 acc[4];
    #pragma unroll
    for (int i = 0; i < 4; ++i) acc[i] = (f32x2){0.f, 0.f};
    spmm_core8(rp, scv, h8, row, f, acc);

    float c0 = coe[0];
    float ch = coe[row < NA ? ihA : ihP];
    float ca = coe[row < NA ? iaA : iaP];
    long o = ((long)row << 7) + f;
    uint4 xv = *(const uint4*)(Xbf + o);
    uint4 hs = *(const uint4*)(hbf + o);
    float r[8];
    r[0] = c0 * bflo(xv.x) + ch * bflo(hs.x) + ca * acc[0].x;
    r[1] = c0 * bfhi(xv.x) + ch * bfhi(hs.x) + ca * acc[0].y;
    r[2] = c0 * bflo(xv.y) + ch * bflo(hs.y) + ca * acc[1].x;
    r[3] = c0 * bfhi(xv.y) + ch * bfhi(hs.y) + ca * acc[1].y;
    r[4] = c0 * bflo(xv.z) + ch * bflo(hs.z) + ca * acc[2].x;
    r[5] = c0 * bfhi(xv.z) + ch * bfhi(hs.z) + ca * acc[2].y;
    r[6] = c0 * bflo(xv.w) + ch * bflo(hs.w) + ca * acc[3].x;
    r[7] = c0 * bfhi(xv.w) + ch * bfhi(hs.w) + ca * acc[3].y;
    uint4 ob;
    ob.x = (unsigned)f2bf(r[0]) | ((unsigned)f2bf(r[1]) << 16);
    ob.y = (unsigned)f2bf(r[2]) | ((unsigned)f2bf(r[3]) << 16);
    ob.z = (unsigned)f2bf(r[4]) | ((unsigned)f2bf(r[5]) << 16);
    ob.w = (unsigned)f2bf(r[6]) | ((unsigned)f2bf(r[7]) << 16);
    *(uint4*)(Xbf + o) = ob;
    uint2 o8;
    o8.x = pk_fp8x4(r[0], r[1], r[2], r[3]);
    o8.y = pk_fp8x4(r[4], r[5], r[6], r[7]);
    *(uint2*)(X8 + o) = o8;
}

// pass-2 update fused with final GEMM:
//   res2(fp32) = c0*Xbf + c_h[seg]*hbf + c_2nd[seg]*(M @ h8)  -> LDS
//   out[row] = res2[row] @ W2 + b2     (res2 never hits HBM)
__global__ __launch_bounds__(256) void spmm_update_out(const int* __restrict__ rp,
                                                       const int2* __restrict__ scv,
                                                       const unsigned char* __restrict__ h8,
                                                       const unsigned short* __restrict__ hbf,
                                                       const unsigned short* __restrict__ Xbf,
                                                       const float* __restrict__ coe,
                                                       const float* __restrict__ W2,
                                                       const float* __restrict__ b2,
                                                       float* __restrict__ out,
                                                       int ihA, int iaA, int ihP, int iaP,
                                                       int NA, int R) {
    __shared__ float xs[16 * 132];
    __shared__ float wT[16 * 132];   // wT[c][k] = W2[k][c]
    __shared__ float bs[16];
    int t = threadIdx.x;
    #pragma unroll
    for (int i = 0; i < 8; ++i) {
        int idx = i * 256 + t;                // 2048 = 128*16
        wT[(idx & 15) * 132 + (idx >> 4)] = W2[idx];
    }
    if (t < 16) bs[t] = b2[t];

    int lane = t & 63;
    int rl = (t >> 6) * 4 + (lane >> 4);
    int row = blockIdx.x * 16 + rl;
    int f = (lane & 15) << 3;
    if (row < R) {
        f32x2 acc[4];
        #pragma unroll
        for (int i = 0; i < 4; ++i) acc[i] = (f32x2){0.f, 0.f};
        spmm_core8(rp, scv, h8, row, f, acc);
        float c0 = coe[0];
        float ch = coe[row < NA ? ihA : ihP];
        float ca = coe[row < NA ? iaA : iaP];
        long o = ((long)row << 7) + f;
        uint4 xv = *(const uint4*)(Xbf + o);
        uint4 hs = *(const uint4*)(hbf + o);
        float* x = &xs[rl * 132 + f];
        x[0] = c0 * bflo(xv.x) + ch * bflo(hs.x) + ca * acc[0].x;
        x[1] = c0 * bfhi(xv.x) + ch * bfhi(hs.x) + ca * acc[0].y;
        x[2] = c0 * bflo(xv.y) + ch * bflo(hs.y) + ca * acc[1].x;
        x[3] = c0 * bfhi(xv.y) + ch * bfhi(hs.y) + ca * acc[1].y;
        x[4] = c0 * bflo(xv.z) + ch * bflo(hs.z) + ca * acc[2].x;
        x[5] = c0 * bfhi(xv.z) + ch * bfhi(hs.z) + ca * acc[2].y;
        x[6] = c0 * bflo(xv.w) + ch * bflo(hs.w) + ca * acc[3].x;
        x[7] = c0 * bfhi(xv.w) + ch * bfhi(hs.w) + ca * acc[3].y;
    }
    __syncthreads();
    int orl = t >> 4, c = t & 15;
    long orow = (long)blockIdx.x * 16 + orl;
    if (orow < R) {
        const float* xrow = &xs[orl * 132];
        const float* wrow = &wT[c * 132];
        f32x4 a4 = {0.f, 0.f, 0.f, 0.f};
        #pragma unroll 8
        for (int k = 0; k < 128; k += 4) {
            f32x4 xv = *(const f32x4*)(xrow + k);
            f32x4 wv = *(const f32x4*)(wrow + k);
            a4 = __builtin_elementwise_fma(xv, wv, a4);
        }
        out[orow * 16 + c] = a4.x + a4.y + a4.z + a4.w + bs[c];
    }
}

extern "C" void kernel_launch(void* const* d_in, const int* in_sizes, int n_in,
                              void* d_out, int out_size, void* d_ws, size_t ws_size,
                              hipStream_t stream) {
    const float* x0  = (const float*)d_in[0];
    const float* x1  = (const float*)d_in[1];
    const float* vap = (const float*)d_in[2];
    const float* vpa = (const float*)d_in[3];
    const int*   rap = (const int*)d_in[4];
    const int*   cap = (const int*)d_in[5];
    const int*   rpa = (const int*)d_in[6];
    const int*   cpa = (const int*)d_in[7];
    const float* Wp0 = (const float*)d_in[8];
    const float* Wp1 = (const float*)d_in[9];
    const float* W1  = (const float*)d_in[10];
    const float* b1  = (const float*)d_in[11];
    const float* W2  = (const float*)d_in[12];
    const float* b2  = (const float*)d_in[13];
    const float* coe = (const float*)d_in[14];
    float* out = (float*)d_out;

    const int NA = in_sizes[0] / 128;
    const int NP = in_sizes[1] / 128;
    const int N  = NA + NP;
    const int E  = in_sizes[2];
    const int E2 = 2 * E;

    char* p = (char*)d_ws;
    auto alloc = [&](size_t bytes) {
        char* r = p;
        p += (bytes + 255) & ~(size_t)255;
        return r;
    };
    unsigned short* Xbf = (unsigned short*)alloc((size_t)N * 128 * 2);
    unsigned short* hbf = (unsigned short*)alloc((size_t)N * 128 * 2);
    unsigned char* X8 = (unsigned char*)alloc((size_t)N * 128);
    unsigned char* h8 = (unsigned char*)alloc((size_t)N * 128);
    float* M0  = (float*)alloc(128 * 128 * 4);
    float* M1  = (float*)alloc(128 * 128 * 4);
    int* cnt   = (int*)alloc((size_t)N * 4);
    int* rp    = (int*)alloc((size_t)(N + 1) * 4);
    int* bt    = (int*)alloc(64 * 4);
    int* bo    = (int*)alloc(64 * 4);
    int2* scv  = (int2*)alloc((size_t)E2 * 8);
    int* bcur  = (int*)alloc(512 * 4);
    if ((size_t)(p - (char*)d_ws) > ws_size) return;

    // tmp partition buffer aliases Xbf (Xbf written only after CSR build);
    // E2*8 = 32 MB <= N*256B = 64 MB
    int2* tmp = (int2*)Xbf;

    const int nbuck = (N + 511) >> 9;
    const int pg = (E + 4095) / 4096;

    // ---- unified CSR build ----
    hipMemsetAsync(cnt, 0, (size_t)N * 4, stream);
    const int cg = (E / 4 + 255) / 256;
    count_rows<<<cg, 256, 0, stream>>>(rap, E, cnt);
    count_rows<<<cg, 256, 0, stream>>>(rpa, E, cnt);
    int B = (N + 4095) / 4096;
    scan1<<<B, 256, 0, stream>>>(cnt, N, rp, bt);
    scan2<<<1, 64, 0, stream>>>(bt, B, bo, rp, N, E2);
    scan3<<<(N + 255) / 256, 256, 0, stream>>>(rp, bo, N);
    binit<<<2, 256, 0, stream>>>(rp, N, nbuck, bcur);
    partition_edges<<<pg, 256, 0, stream>>>(rap, cap, vap, E, nbuck, bcur, tmp);
    partition_edges<<<pg, 256, 0, stream>>>(rpa, cpa, vpa, E, nbuck, bcur, tmp);
    place_edges<<<nbuck, 1024, 0, stream>>>(rp, tmp, N, scv);

    // ---- dense front-end (Xbf written AFTER tmp aliasing done) ----
    fuse_w<<<256, 128, 0, stream>>>(Wp0, Wp1, W1, M0, M1);
    gemm_relu_norm<<<(NA + 31) / 32, 256, 0, stream>>>(x0, M0, b1, Xbf, X8, NA);
    gemm_relu_norm<<<(NP + 31) / 32, 256, 0, stream>>>(
        x1, M1, b1, Xbf + (size_t)NA * 128, X8 + (size_t)NA * 128, NP);

    const int sg = (N + 15) / 16;

    // ---- pass 1 (AP first): A rows coe1/coe3, P rows coe2/coe4 ----
    spmm_plain<<<sg, 256, 0, stream>>>(rp, scv, X8, hbf, h8, N);
    spmm_update<<<sg, 256, 0, stream>>>(rp, scv, h8, hbf, Xbf, X8, coe, 1, 3, 2, 4, NA, N);

    // ---- pass 2 (PA first) fused with out = res2 @ W2 + b2 ----
    spmm_plain<<<sg, 256, 0, stream>>>(rp, scv, X8, hbf, h8, N);
    spmm_update_out<<<sg, 256, 0, stream>>>(rp, scv, h8, hbf, Xbf, coe,
                                            W2, b2, out, 2, 4, 1, 3, NA, N);
}

// Round 6
// 984.475 us; speedup vs baseline: 1.1089x; 1.0146x over previous
//
#include <hip/hip_runtime.h>
#include <hip/hip_bf16.h>

// PSHGCN on MI355X — round 11:
//  * gemm_relu_norm inner loop rewritten: k-step 4 with float4 xs reads
//    (LDS ops per 64 FMAs: 20 -> 8; xs reads are wave-broadcast) and W
//    staged in 32-row quarters (LDS 48 KB -> 32 KB, 3 -> 5 blocks/CU).
//    Round-10 counters: 43 TF of 157 fp32 peak, VALUBusy 64%, occ 29%,
//    HBM 10% — pure VALU/LDS-issue limited. FMA chain order preserved
//    (bitwise-identical output).
//  * place_edges LDS-histogram scheme confirmed (dropped out of top-5).
//  * everything else unchanged from round 10.

typedef float f32x2 __attribute__((ext_vector_type(2)));
typedef float f32x4 __attribute__((ext_vector_type(4)));

__device__ inline unsigned short f2bf(float x) {
    unsigned b = __float_as_uint(x);
    unsigned r = (b + 0x7fffu + ((b >> 16) & 1u)) >> 16;
    return (unsigned short)r;
}
__device__ inline float bflo(unsigned u) { return __uint_as_float(u << 16); }
__device__ inline float bfhi(unsigned u) { return __uint_as_float(u & 0xffff0000u); }

// pack 4 floats -> 4 fp8 e4m3 bytes (a in byte0 .. d in byte3)
__device__ inline unsigned pk_fp8x4(float a, float b, float c, float d) {
    int v = __builtin_amdgcn_cvt_pk_fp8_f32(a, b, 0, false);
    v = __builtin_amdgcn_cvt_pk_fp8_f32(c, d, v, true);
    return (unsigned)v;
}

// ---------------- dense: M = Wp @ W1 (two 128x128x128) ----------------
__global__ __launch_bounds__(128) void fuse_w(const float* __restrict__ Wp0,
                                              const float* __restrict__ Wp1,
                                              const float* __restrict__ W1,
                                              float* __restrict__ M0,
                                              float* __restrict__ M1) {
    int m = blockIdx.x >> 7;
    int i = blockIdx.x & 127;
    const float* Wp = m ? Wp1 : Wp0;
    float* M = m ? M1 : M0;
    __shared__ float r[128];
    int t = threadIdx.x;
    r[t] = Wp[i * 128 + t];
    __syncthreads();
    float acc = 0.f;
    #pragma unroll 8
    for (int k = 0; k < 128; ++k) acc += r[k] * W1[k * 128 + t];
    M[i * 128 + t] = acc;
}

// ---- dense: Xbf/X8 = normalize(relu(xin @ M + b1))  (bf16 + fp8 out) ----
__global__ __launch_bounds__(256) void gemm_relu_norm(const float* __restrict__ xin,
                                                      const float* __restrict__ M,
                                                      const float* __restrict__ b1,
                                                      unsigned short* __restrict__ xbf,
                                                      unsigned char* __restrict__ x8,
                                                      int nrows) {
    __shared__ float Wl[32 * 128];    // one 32-row quarter of M
    __shared__ float xs[32 * 128];
    int t = threadIdx.x;
    long row0 = (long)blockIdx.x * 32;
    int rows_this = nrows - (int)row0;
    if (rows_this > 32) rows_this = 32;

    #pragma unroll
    for (int it = 0; it < 4; ++it) {
        int g4 = it * 256 + t;
        int g = g4 * 4;
        int rl = g >> 7, c = g & 127;
        float4 val = {0.f, 0.f, 0.f, 0.f};
        if (rl < rows_this) val = *(const float4*)(xin + (row0 + rl) * 128 + c);
        *(float4*)&xs[rl * 128 + c] = val;
    }

    int r0 = (t >> 5) * 4;
    int c0 = (t & 31) * 4;
    float acc[4][4];
    #pragma unroll
    for (int i = 0; i < 4; ++i)
        #pragma unroll
        for (int j = 0; j < 4; ++j) acc[i][j] = 0.f;

    for (int q = 0; q < 4; ++q) {
        __syncthreads();
        #pragma unroll
        for (int it = 0; it < 4; ++it) {
            int g4 = it * 256 + t;          // 1024 float4 = 32*128 floats
            ((float4*)Wl)[g4] = ((const float4*)(M + q * 4096))[g4];
        }
        __syncthreads();
        #pragma unroll 2
        for (int k = 0; k < 32; k += 4) {
            float4 w0 = *(float4*)&Wl[(k + 0) * 128 + c0];
            float4 w1 = *(float4*)&Wl[(k + 1) * 128 + c0];
            float4 w2 = *(float4*)&Wl[(k + 2) * 128 + c0];
            float4 w3 = *(float4*)&Wl[(k + 3) * 128 + c0];
            int kk = q * 32 + k;
            #pragma unroll
            for (int i = 0; i < 4; ++i) {
                float4 xv = *(float4*)&xs[(r0 + i) * 128 + kk];
                // keep sequential-k accumulation order (bitwise == old code)
                acc[i][0] += xv.x * w0.x; acc[i][1] += xv.x * w0.y;
                acc[i][2] += xv.x * w0.z; acc[i][3] += xv.x * w0.w;
                acc[i][0] += xv.y * w1.x; acc[i][1] += xv.y * w1.y;
                acc[i][2] += xv.y * w1.z; acc[i][3] += xv.y * w1.w;
                acc[i][0] += xv.z * w2.x; acc[i][1] += xv.z * w2.y;
                acc[i][2] += xv.z * w2.z; acc[i][3] += xv.z * w2.w;
                acc[i][0] += xv.w * w3.x; acc[i][1] += xv.w * w3.y;
                acc[i][2] += xv.w * w3.z; acc[i][3] += xv.w * w3.w;
            }
        }
    }

    float4 bb = *(const float4*)(b1 + c0);
    #pragma unroll
    for (int i = 0; i < 4; ++i) {
        float o0 = acc[i][0] + bb.x; o0 = o0 > 0.f ? o0 : 0.f;
        float o1 = acc[i][1] + bb.y; o1 = o1 > 0.f ? o1 : 0.f;
        float o2 = acc[i][2] + bb.z; o2 = o2 > 0.f ? o2 : 0.f;
        float o3 = acc[i][3] + bb.w; o3 = o3 > 0.f ? o3 : 0.f;
        float s = o0 + o1 + o2 + o3;
        #pragma unroll
        for (int m = 16; m >= 1; m >>= 1) s += __shfl_xor(s, m);
        float mean = s * (1.0f / 128.0f);
        float d0 = o0 - mean, d1 = o1 - mean, d2 = o2 - mean, d3 = o3 - mean;
        float q = d0 * d0 + d1 * d1 + d2 * d2 + d3 * d3;
        #pragma unroll
        for (int m = 16; m >= 1; m >>= 1) q += __shfl_xor(q, m);
        float inv = 0.f;
        if (q > 0.f) inv = 1.0f / sqrtf(q * (1.0f / 127.0f));
        int row = r0 + i;
        if (row < rows_this) {
            float z0 = d0 * inv, z1 = d1 * inv, z2 = d2 * inv, z3 = d3 * inv;
            uint2 pk;
            pk.x = (unsigned)f2bf(z0) | ((unsigned)f2bf(z1) << 16);
            pk.y = (unsigned)f2bf(z2) | ((unsigned)f2bf(z3) << 16);
            *(uint2*)(xbf + (row0 + row) * 128 + c0) = pk;
            *(unsigned*)(x8 + (row0 + row) * 128 + c0) = pk_fp8x4(z0, z1, z2, z3);
        }
    }
}

// ---------------- CSR build (unified, N rows, global cols) ----------------
__global__ __launch_bounds__(256) void count_rows(const int* __restrict__ rows, int E,
                                                  int* __restrict__ cnt) {
    int i = (blockIdx.x * 256 + threadIdx.x) * 4;
    if (i + 4 <= E) {
        int4 r = *(const int4*)(rows + i);
        atomicAdd(&cnt[r.x], 1);
        atomicAdd(&cnt[r.y], 1);
        atomicAdd(&cnt[r.z], 1);
        atomicAdd(&cnt[r.w], 1);
    } else {
        for (; i < E; ++i) atomicAdd(&cnt[rows[i]], 1);
    }
}

__global__ __launch_bounds__(256) void scan1(const int* __restrict__ cnt, int R,
                                             int* __restrict__ rp, int* __restrict__ bt) {
    __shared__ int lds[256];
    int t = threadIdx.x, b = blockIdx.x;
    int base = b * 4096 + t * 16;
    int v[16];
    int s = 0;
    #pragma unroll
    for (int i = 0; i < 16; ++i) {
        int idx = base + i;
        int c = (idx < R) ? cnt[idx] : 0;
        v[i] = s;
        s += c;
    }
    lds[t] = s;
    __syncthreads();
    for (int off = 1; off < 256; off <<= 1) {
        int x = (t >= off) ? lds[t - off] : 0;
        __syncthreads();
        lds[t] += x;
        __syncthreads();
    }
    int excl = lds[t] - s;
    #pragma unroll
    for (int i = 0; i < 16; ++i) {
        int idx = base + i;
        if (idx < R) rp[idx] = excl + v[i];
    }
    if (t == 0) bt[b] = lds[255];
}

__global__ __launch_bounds__(64) void scan2(const int* __restrict__ bt, int B,
                                            int* __restrict__ bo, int* __restrict__ rp,
                                            int R, int E2) {
    int t = threadIdx.x;
    int v = (t < B) ? bt[t] : 0;
    int inc = v;
    #pragma unroll
    for (int off = 1; off < 64; off <<= 1) {
        int y = __shfl_up(inc, off);
        if (t >= off) inc += y;
    }
    if (t < B) bo[t] = inc - v;
    if (t == 0) rp[R] = E2;
}

__global__ __launch_bounds__(256) void scan3(int* __restrict__ rp, const int* __restrict__ bo,
                                             int R) {
    int i = blockIdx.x * 256 + threadIdx.x;
    if (i < R) rp[i] = rp[i] + bo[i >> 12];
}

__global__ __launch_bounds__(256) void binit(const int* __restrict__ rp, int NR,
                                             int nbuck, int* __restrict__ bcur) {
    int b = blockIdx.x * 256 + threadIdx.x;
    if (b < nbuck) {
        int r = b << 9;
        if (r > NR) r = NR;
        bcur[b] = rp[r];
    }
}

// ---- phase 1: partition edges into 512-row buckets (L2-local writes) ----
__global__ __launch_bounds__(256) void partition_edges(const int* __restrict__ rows,
                                                       const int* __restrict__ cols,
                                                       const float* __restrict__ vals,
                                                       int E, int nbuck,
                                                       int* __restrict__ bcur,
                                                       int2* __restrict__ tmp) {
    __shared__ int hist[512];
    __shared__ int gbase[512];
    __shared__ int cnt2[512];
    int t = threadIdx.x;
    for (int b = t; b < nbuck; b += 256) { hist[b] = 0; cnt2[b] = 0; }
    __syncthreads();
    long base = (long)blockIdx.x * 4096;
    #pragma unroll
    for (int k = 0; k < 16; ++k) {
        long i = base + k * 256 + t;
        if (i < E) atomicAdd(&hist[rows[i] >> 9], 1);
    }
    __syncthreads();
    for (int b = t; b < nbuck; b += 256) {
        int h = hist[b];
        gbase[b] = h ? atomicAdd(&bcur[b], h) : 0;
    }
    __syncthreads();
    #pragma unroll
    for (int k = 0; k < 16; ++k) {
        long i = base + k * 256 + t;
        if (i < E) {
            int rl = rows[i];
            int b = rl >> 9;
            int rank = atomicAdd(&cnt2[b], 1);
            int2 rec;
            rec.x = ((rl - (b << 9)) << 18) | cols[i];
            rec.y = __float_as_int(vals[i]);
            tmp[gbase[b] + rank] = rec;
        }
    }
}

// ---- phase 2: exact-position scatter within one bucket, LDS atomics only ----
__global__ __launch_bounds__(1024) void place_edges(const int* __restrict__ rp,
                                                    const int2* __restrict__ tmp,
                                                    int NR,
                                                    int2* __restrict__ scv) {
    __shared__ int hist[512];
    __shared__ int hoff[512];
    int b = blockIdx.x;
    int srow = b << 9;
    int erow = srow + 512;
    if (erow > NR) erow = NR;
    int start = rp[srow], endp = rp[erow];
    int t = threadIdx.x;
    if (t < 512) hist[t] = 0;
    __syncthreads();

    // pass 1: per-row histogram in LDS
    for (int i = start + t; i < endp; i += 1024)
        atomicAdd(&hist[tmp[i].x >> 18], 1);
    __syncthreads();

    // prefix-sum (Hillis-Steele, inclusive) over 512 counters
    if (t < 512) hoff[t] = hist[t];
    __syncthreads();
    for (int off = 1; off < 512; off <<= 1) {
        int v = 0;
        if (t < 512 && t >= off) v = hoff[t - off];
        __syncthreads();
        if (t < 512) hoff[t] += v;
        __syncthreads();
    }
    // convert to running cursor = global base + exclusive prefix
    if (t < 512) hoff[t] = start + hoff[t] - hist[t];
    __syncthreads();

    // pass 2: rank via LDS atomic, scatter to exact CSR slot (tmp is L2-hot)
    int i = start + t;
    for (; i + 3 * 1024 < endp; i += 4 * 1024) {
        int2 a0 = tmp[i];
        int2 a1 = tmp[i + 1024];
        int2 a2 = tmp[i + 2048];
        int2 a3 = tmp[i + 3072];
        int p0 = atomicAdd(&hoff[a0.x >> 18], 1);
        int p1 = atomicAdd(&hoff[a1.x >> 18], 1);
        int p2 = atomicAdd(&hoff[a2.x >> 18], 1);
        int p3 = atomicAdd(&hoff[a3.x >> 18], 1);
        int2 o0; o0.x = a0.x & 0x3ffff; o0.y = a0.y;
        int2 o1; o1.x = a1.x & 0x3ffff; o1.y = a1.y;
        int2 o2; o2.x = a2.x & 0x3ffff; o2.y = a2.y;
        int2 o3; o3.x = a3.x & 0x3ffff; o3.y = a3.y;
        scv[p0] = o0;
        scv[p1] = o1;
        scv[p2] = o2;
        scv[p3] = o3;
    }
    for (; i < endp; i += 1024) {
        int2 rec = tmp[i];
        int p = atomicAdd(&hoff[rec.x >> 18], 1);
        int2 o;
        o.x = rec.x & 0x3ffff;
        o.y = rec.y;
        scv[p] = o;
    }
}

// decode one fp8 row-segment (8 vals in uint2) and packed-fma into acc[4]
#define DEC_FMA(qq, vv) do {                                                        \
    f32x2 vp_ = {(vv), (vv)};                                                       \
    acc[0] = __builtin_elementwise_fma(vp_, __builtin_amdgcn_cvt_pk_f32_fp8((qq).x, false), acc[0]); \
    acc[1] = __builtin_elementwise_fma(vp_, __builtin_amdgcn_cvt_pk_f32_fp8((qq).x, true),  acc[1]); \
    acc[2] = __builtin_elementwise_fma(vp_, __builtin_amdgcn_cvt_pk_f32_fp8((qq).y, false), acc[2]); \
    acc[3] = __builtin_elementwise_fma(vp_, __builtin_amdgcn_cvt_pk_f32_fp8((qq).y, true),  acc[3]); \
} while (0)

// ---- SpMM core: one row per 16-lane quarter, unroll x8, fp8 gathers ----
__device__ inline void spmm_core8(const int* __restrict__ rp,
                                  const int2* __restrict__ scv,
                                  const unsigned char* __restrict__ g8,
                                  int row, int f, f32x2* acc) {
    int beg = rp[row], end = rp[row + 1];
    int j = beg;
    // align to even index so int4 (edge-pair) loads are 16B-aligned
    if ((j & 1) && j < end) {
        int2 r0 = scv[j];
        uint2 q0 = *(const uint2*)(g8 + ((long)r0.x << 7) + f);
        float v0 = __int_as_float(r0.y);
        DEC_FMA(q0, v0);
        ++j;
    }
    for (; j + 8 <= end; j += 8) {
        int4 s01 = *(const int4*)(scv + j);
        int4 s23 = *(const int4*)(scv + j + 2);
        int4 s45 = *(const int4*)(scv + j + 4);
        int4 s67 = *(const int4*)(scv + j + 6);
        uint2 q0 = *(const uint2*)(g8 + ((long)s01.x << 7) + f);
        uint2 q1 = *(const uint2*)(g8 + ((long)s01.z << 7) + f);
        uint2 q2 = *(const uint2*)(g8 + ((long)s23.x << 7) + f);
        uint2 q3 = *(const uint2*)(g8 + ((long)s23.z << 7) + f);
        uint2 q4 = *(const uint2*)(g8 + ((long)s45.x << 7) + f);
        uint2 q5 = *(const uint2*)(g8 + ((long)s45.z << 7) + f);
        uint2 q6 = *(const uint2*)(g8 + ((long)s67.x << 7) + f);
        uint2 q7 = *(const uint2*)(g8 + ((long)s67.z << 7) + f);
        DEC_FMA(q0, __int_as_float(s01.y));
        DEC_FMA(q1, __int_as_float(s01.w));
        DEC_FMA(q2, __int_as_float(s23.y));
        DEC_FMA(q3, __int_as_float(s23.w));
        DEC_FMA(q4, __int_as_float(s45.y));
        DEC_FMA(q5, __int_as_float(s45.w));
        DEC_FMA(q6, __int_as_float(s67.y));
        DEC_FMA(q7, __int_as_float(s67.w));
    }
    for (; j + 2 <= end; j += 2) {
        int4 s01 = *(const int4*)(scv + j);
        uint2 q0 = *(const uint2*)(g8 + ((long)s01.x << 7) + f);
        uint2 q1 = *(const uint2*)(g8 + ((long)s01.z << 7) + f);
        DEC_FMA(q0, __int_as_float(s01.y));
        DEC_FMA(q1, __int_as_float(s01.w));
    }
    if (j < end) {
        int2 r0 = scv[j];
        uint2 q0 = *(const uint2*)(g8 + ((long)r0.x << 7) + f);
        float v0 = __int_as_float(r0.y);
        DEC_FMA(q0, v0);
    }
}

// h = M @ X : gathers X8 (fp8), writes h as bf16 (stream copy) + fp8 (gather copy)
__global__ __launch_bounds__(256) void spmm_plain(const int* __restrict__ rp,
                                                  const int2* __restrict__ scv,
                                                  const unsigned char* __restrict__ x8,
                                                  unsigned short* __restrict__ houtbf,
                                                  unsigned char* __restrict__ hout8,
                                                  int R) {
    int wave = blockIdx.x * 4 + (threadIdx.x >> 6);
    int lane = threadIdx.x & 63;
    int row = wave * 4 + (lane >> 4);
    if (row >= R) return;
    int f = (lane & 15) << 3;
    f32x2 acc[4];
    #pragma unroll
    for (int i = 0; i < 4; ++i) acc[i] = (f32x2){0.f, 0.f};
    spmm_core8(rp, scv, x8, row, f, acc);
    uint4 o;
    o.x = (unsigned)f2bf(acc[0].x) | ((unsigned)f2bf(acc[0].y) << 16);
    o.y = (unsigned)f2bf(acc[1].x) | ((unsigned)f2bf(acc[1].y) << 16);
    o.z = (unsigned)f2bf(acc[2].x) | ((unsigned)f2bf(acc[2].y) << 16);
    o.w = (unsigned)f2bf(acc[3].x) | ((unsigned)f2bf(acc[3].y) << 16);
    *(uint4*)(houtbf + ((long)row << 7) + f) = o;
    uint2 o8;
    o8.x = pk_fp8x4(acc[0].x, acc[0].y, acc[1].x, acc[1].y);
    o8.y = pk_fp8x4(acc[2].x, acc[2].y, acc[3].x, acc[3].y);
    *(uint2*)(hout8 + ((long)row << 7) + f) = o8;
}

// pass-1 update: X = c0*X + c_h[seg]*h + c_2nd[seg]*(M @ h)
// gathers h8 (fp8); streams Xbf,hbf (bf16); writes Xbf (bf16) + X8 (fp8)
__global__ __launch_bounds__(256) void spmm_update(const int* __restrict__ rp,
                                                   const int2* __restrict__ scv,
                                                   const unsigned char* __restrict__ h8,
                                                   const unsigned short* __restrict__ hbf,
                                                   unsigned short* __restrict__ Xbf,
                                                   unsigned char* __restrict__ X8,
                                                   const float* __restrict__ coe,
                                                   int ihA, int iaA, int ihP, int iaP,
                                                   int NA, int R) {
    int wave = blockIdx.x * 4 + (threadIdx.x >> 6);
    int lane = threadIdx.x & 63;
    int row = wave * 4 + (lane >> 4);
    if (row >= R) return;
    int f = (lane & 15) << 3;
    f32x2 acc[4];
    #pragma unroll
    for (int i = 0; i < 4; ++i) acc[i] = (f32x2){0.f, 0.f};
    spmm_core8(rp, scv, h8, row, f, acc);

    float c0 = coe[0];
    float ch = coe[row < NA ? ihA : ihP];
    float ca = coe[row < NA ? iaA : iaP];
    long o = ((long)row << 7) + f;
    uint4 xv = *(const uint4*)(Xbf + o);
    uint4 hs = *(const uint4*)(hbf + o);
    float r[8];
    r[0] = c0 * bflo(xv.x) + ch * bflo(hs.x) + ca * acc[0].x;
    r[1] = c0 * bfhi(xv.x) + ch * bfhi(hs.x) + ca * acc[0].y;
    r[2] = c0 * bflo(xv.y) + ch * bflo(hs.y) + ca * acc[1].x;
    r[3] = c0 * bfhi(xv.y) + ch * bfhi(hs.y) + ca * acc[1].y;
    r[4] = c0 * bflo(xv.z) + ch * bflo(hs.z) + ca * acc[2].x;
    r[5] = c0 * bfhi(xv.z) + ch * bfhi(hs.z) + ca * acc[2].y;
    r[6] = c0 * bflo(xv.w) + ch * bflo(hs.w) + ca * acc[3].x;
    r[7] = c0 * bfhi(xv.w) + ch * bfhi(hs.w) + ca * acc[3].y;
    uint4 ob;
    ob.x = (unsigned)f2bf(r[0]) | ((unsigned)f2bf(r[1]) << 16);
    ob.y = (unsigned)f2bf(r[2]) | ((unsigned)f2bf(r[3]) << 16);
    ob.z = (unsigned)f2bf(r[4]) | ((unsigned)f2bf(r[5]) << 16);
    ob.w = (unsigned)f2bf(r[6]) | ((unsigned)f2bf(r[7]) << 16);
    *(uint4*)(Xbf + o) = ob;
    uint2 o8;
    o8.x = pk_fp8x4(r[0], r[1], r[2], r[3]);
    o8.y = pk_fp8x4(r[4], r[5], r[6], r[7]);
    *(uint2*)(X8 + o) = o8;
}

// pass-2 update fused with final GEMM:
//   res2(fp32) = c0*Xbf + c_h[seg]*hbf + c_2nd[seg]*(M @ h8)  -> LDS
//   out[row] = res2[row] @ W2 + b2     (res2 never hits HBM)
__global__ __launch_bounds__(256) void spmm_update_out(const int* __restrict__ rp,
                                                       const int2* __restrict__ scv,
                                                       const unsigned char* __restrict__ h8,
                                                       const unsigned short* __restrict__ hbf,
                                                       const unsigned short* __restrict__ Xbf,
                                                       const float* __restrict__ coe,
                                                       const float* __restrict__ W2,
                                                       const float* __restrict__ b2,
                                                       float* __restrict__ out,
                                                       int ihA, int iaA, int ihP, int iaP,
                                                       int NA, int R) {
    __shared__ float xs[16 * 132];
    __shared__ float wT[16 * 132];   // wT[c][k] = W2[k][c]
    __shared__ float bs[16];
    int t = threadIdx.x;
    #pragma unroll
    for (int i = 0; i < 8; ++i) {
        int idx = i * 256 + t;                // 2048 = 128*16
        wT[(idx & 15) * 132 + (idx >> 4)] = W2[idx];
    }
    if (t < 16) bs[t] = b2[t];

    int lane = t & 63;
    int rl = (t >> 6) * 4 + (lane >> 4);
    int row = blockIdx.x * 16 + rl;
    int f = (lane & 15) << 3;
    if (row < R) {
        f32x2 acc[4];
        #pragma unroll
        for (int i = 0; i < 4; ++i) acc[i] = (f32x2){0.f, 0.f};
        spmm_core8(rp, scv, h8, row, f, acc);
        float c0 = coe[0];
        float ch = coe[row < NA ? ihA : ihP];
        float ca = coe[row < NA ? iaA : iaP];
        long o = ((long)row << 7) + f;
        uint4 xv = *(const uint4*)(Xbf + o);
        uint4 hs = *(const uint4*)(hbf + o);
        float* x = &xs[rl * 132 + f];
        x[0] = c0 * bflo(xv.x) + ch * bflo(hs.x) + ca * acc[0].x;
        x[1] = c0 * bfhi(xv.x) + ch * bfhi(hs.x) + ca * acc[0].y;
        x[2] = c0 * bflo(xv.y) + ch * bflo(hs.y) + ca * acc[1].x;
        x[3] = c0 * bfhi(xv.y) + ch * bfhi(hs.y) + ca * acc[1].y;
        x[4] = c0 * bflo(xv.z) + ch * bflo(hs.z) + ca * acc[2].x;
        x[5] = c0 * bfhi(xv.z) + ch * bfhi(hs.z) + ca * acc[2].y;
        x[6] = c0 * bflo(xv.w) + ch * bflo(hs.w) + ca * acc[3].x;
        x[7] = c0 * bfhi(xv.w) + ch * bfhi(hs.w) + ca * acc[3].y;
    }
    __syncthreads();
    int orl = t >> 4, c = t & 15;
    long orow = (long)blockIdx.x * 16 + orl;
    if (orow < R) {
        const float* xrow = &xs[orl * 132];
        const float* wrow = &wT[c * 132];
        f32x4 a4 = {0.f, 0.f, 0.f, 0.f};
        #pragma unroll 8
        for (int k = 0; k < 128; k += 4) {
            f32x4 xv = *(const f32x4*)(xrow + k);
            f32x4 wv = *(const f32x4*)(wrow + k);
            a4 = __builtin_elementwise_fma(xv, wv, a4);
        }
        out[orow * 16 + c] = a4.x + a4.y + a4.z + a4.w + bs[c];
    }
}

extern "C" void kernel_launch(void* const* d_in, const int* in_sizes, int n_in,
                              void* d_out, int out_size, void* d_ws, size_t ws_size,
                              hipStream_t stream) {
    const float* x0  = (const float*)d_in[0];
    const float* x1  = (const float*)d_in[1];
    const float* vap = (const float*)d_in[2];
    const float* vpa = (const float*)d_in[3];
    const int*   rap = (const int*)d_in[4];
    const int*   cap = (const int*)d_in[5];
    const int*   rpa = (const int*)d_in[6];
    const int*   cpa = (const int*)d_in[7];
    const float* Wp0 = (const float*)d_in[8];
    const float* Wp1 = (const float*)d_in[9];
    const float* W1  = (const float*)d_in[10];
    const float* b1  = (const float*)d_in[11];
    const float* W2  = (const float*)d_in[12];
    const float* b2  = (const float*)d_in[13];
    const float* coe = (const float*)d_in[14];
    float* out = (float*)d_out;

    const int NA = in_sizes[0] / 128;
    const int NP = in_sizes[1] / 128;
    const int N  = NA + NP;
    const int E  = in_sizes[2];
    const int E2 = 2 * E;

    char* p = (char*)d_ws;
    auto alloc = [&](size_t bytes) {
        char* r = p;
        p += (bytes + 255) & ~(size_t)255;
        return r;
    };
    unsigned short* Xbf = (unsigned short*)alloc((size_t)N * 128 * 2);
    unsigned short* hbf = (unsigned short*)alloc((size_t)N * 128 * 2);
    unsigned char* X8 = (unsigned char*)alloc((size_t)N * 128);
    unsigned char* h8 = (unsigned char*)alloc((size_t)N * 128);
    float* M0  = (float*)alloc(128 * 128 * 4);
    float* M1  = (float*)alloc(128 * 128 * 4);
    int* cnt   = (int*)alloc((size_t)N * 4);
    int* rp    = (int*)alloc((size_t)(N + 1) * 4);
    int* bt    = (int*)alloc(64 * 4);
    int* bo    = (int*)alloc(64 * 4);
    int2* scv  = (int2*)alloc((size_t)E2 * 8);
    int* bcur  = (int*)alloc(512 * 4);
    if ((size_t)(p - (char*)d_ws) > ws_size) return;

    // tmp partition buffer aliases Xbf (Xbf written only after CSR build);
    // E2*8 = 32 MB <= N*256B = 64 MB
    int2* tmp = (int2*)Xbf;

    const int nbuck = (N + 511) >> 9;
    const int pg = (E + 4095) / 4096;

    // ---- unified CSR build ----
    hipMemsetAsync(cnt, 0, (size_t)N * 4, stream);
    const int cg = (E / 4 + 255) / 256;
    count_rows<<<cg, 256, 0, stream>>>(rap, E, cnt);
    count_rows<<<cg, 256, 0, stream>>>(rpa, E, cnt);
    int B = (N + 4095) / 4096;
    scan1<<<B, 256, 0, stream>>>(cnt, N, rp, bt);
    scan2<<<1, 64, 0, stream>>>(bt, B, bo, rp, N, E2);
    scan3<<<(N + 255) / 256, 256, 0, stream>>>(rp, bo, N);
    binit<<<2, 256, 0, stream>>>(rp, N, nbuck, bcur);
    partition_edges<<<pg, 256, 0, stream>>>(rap, cap, vap, E, nbuck, bcur, tmp);
    partition_edges<<<pg, 256, 0, stream>>>(rpa, cpa, vpa, E, nbuck, bcur, tmp);
    place_edges<<<nbuck, 1024, 0, stream>>>(rp, tmp, N, scv);

    // ---- dense front-end (Xbf written AFTER tmp aliasing done) ----
    fuse_w<<<256, 128, 0, stream>>>(Wp0, Wp1, W1, M0, M1);
    gemm_relu_norm<<<(NA + 31) / 32, 256, 0, stream>>>(x0, M0, b1, Xbf, X8, NA);
    gemm_relu_norm<<<(NP + 31) / 32, 256, 0, stream>>>(
        x1, M1, b1, Xbf + (size_t)NA * 128, X8 + (size_t)NA * 128, NP);

    const int sg = (N + 15) / 16;

    // ---- pass 1 (AP first): A rows coe1/coe3, P rows coe2/coe4 ----
    spmm_plain<<<sg, 256, 0, stream>>>(rp, scv, X8, hbf, h8, N);
    spmm_update<<<sg, 256, 0, stream>>>(rp, scv, h8, hbf, Xbf, X8, coe, 1, 3, 2, 4, NA, N);

    // ---- pass 2 (PA first) fused with out = res2 @ W2 + b2 ----
    spmm_plain<<<sg, 256, 0, stream>>>(rp, scv, X8, hbf, h8, N);
    spmm_update_out<<<sg, 256, 0, stream>>>(rp, scv, h8, hbf, Xbf, coe,
                                            W2, b2, out, 2, 4, 1, 3, NA, N);
}

// Round 7
// 913.379 us; speedup vs baseline: 1.1952x; 1.0778x over previous
//
#include <hip/hip_runtime.h>
#include <hip/hip_bf16.h>

// PSHGCN on MI355X — round 12:
//  * gemm_relu_norm moved to bf16 MFMA (16x16x32), replacing the fp32
//    vector-ALU GEMM that plateaued at ~46 TF (round-11 post-mortem:
//    VALUBusy 64%, structure within 2x of the 157 TF fp32 ceiling).
//    Precision: x split into hi+lo bf16 (17-bit effective mantissa),
//    2 MFMAs per B-frag -> only M's single bf16 rounding remains (~0.2%),
//    same order as the existing bf16 storage of z. M converted to
//    bf16-transposed [n][k] inside fuse_w. LDS fragment slots XOR-swizzled
//    (slot ^= row&7) to avoid the 16-way bank conflict of the naive layout.
//  * per block: 64 rows x 128 cols, 4 waves x 16 rows, 8 col-tiles,
//    K=128 in 4 steps; LDS 64 KB (xs_hi 16K + xs_lo 16K + Mt 32K).
//  * SpMM / CSR build / place_edges unchanged from round 11.

typedef float f32x2 __attribute__((ext_vector_type(2)));
typedef float f32x4 __attribute__((ext_vector_type(4)));
typedef short bf16x8 __attribute__((ext_vector_type(8)));

__device__ inline unsigned short f2bf(float x) {
    unsigned b = __float_as_uint(x);
    unsigned r = (b + 0x7fffu + ((b >> 16) & 1u)) >> 16;
    return (unsigned short)r;
}
__device__ inline float bflo(unsigned u) { return __uint_as_float(u << 16); }
__device__ inline float bfhi(unsigned u) { return __uint_as_float(u & 0xffff0000u); }

// pack 4 floats -> 4 fp8 e4m3 bytes (a in byte0 .. d in byte3)
__device__ inline unsigned pk_fp8x4(float a, float b, float c, float d) {
    int v = __builtin_amdgcn_cvt_pk_fp8_f32(a, b, 0, false);
    v = __builtin_amdgcn_cvt_pk_fp8_f32(c, d, v, true);
    return (unsigned)v;
}

// ------- dense: Mt(bf16, transposed [n][k]) = (Wp @ W1)^T -------
__global__ __launch_bounds__(128) void fuse_w(const float* __restrict__ Wp0,
                                              const float* __restrict__ Wp1,
                                              const float* __restrict__ W1,
                                              unsigned short* __restrict__ Mt0,
                                              unsigned short* __restrict__ Mt1) {
    int m = blockIdx.x >> 7;
    int i = blockIdx.x & 127;           // row of M = k index
    const float* Wp = m ? Wp1 : Wp0;
    unsigned short* Mt = m ? Mt1 : Mt0;
    __shared__ float r[128];
    int t = threadIdx.x;
    r[t] = Wp[i * 128 + t];
    __syncthreads();
    float acc = 0.f;
    #pragma unroll 8
    for (int k = 0; k < 128; ++k) acc += r[k] * W1[k * 128 + t];
    Mt[t * 128 + i] = f2bf(acc);        // transposed store: Mt[n][k]
}

// ---- dense (MFMA): Xbf/X8 = normalize(relu(xin @ M + b1)) ----
__global__ __launch_bounds__(256) void gemm_relu_norm(const float* __restrict__ xin,
                                                      const unsigned short* __restrict__ Mt,
                                                      const float* __restrict__ b1,
                                                      unsigned short* __restrict__ xbf,
                                                      unsigned char* __restrict__ x8,
                                                      int nrows) {
    __shared__ char xsh[64 * 256];      // x hi bf16, swizzled 16B slots
    __shared__ char xsl[64 * 256];      // x lo bf16
    __shared__ char mts[128 * 256];     // Mt bf16 [n][k], swizzled
    int t = threadIdx.x;
    long row0 = (long)blockIdx.x * 64;
    int rows_this = nrows - (int)row0;
    if (rows_this > 64) rows_this = 64;

    // stage x: fp32 -> (hi, lo) bf16 split, 16B slots swizzled by row&7
    #pragma unroll
    for (int it = 0; it < 4; ++it) {
        int idx = it * 256 + t;
        int row = idx >> 4, slot = idx & 15;
        float4 v0 = {0.f, 0.f, 0.f, 0.f}, v1 = {0.f, 0.f, 0.f, 0.f};
        if (row < rows_this) {
            v0 = *(const float4*)(xin + (row0 + row) * 128 + slot * 8);
            v1 = *(const float4*)(xin + (row0 + row) * 128 + slot * 8 + 4);
        }
        float vv[8] = {v0.x, v0.y, v0.z, v0.w, v1.x, v1.y, v1.z, v1.w};
        unsigned hw[8], lw[8];
        #pragma unroll
        for (int j = 0; j < 8; ++j) {
            unsigned h = f2bf(vv[j]);
            float hv = __uint_as_float(h << 16);
            hw[j] = h;
            lw[j] = f2bf(vv[j] - hv);
        }
        uint4 ph, pl;
        ph.x = hw[0] | (hw[1] << 16); ph.y = hw[2] | (hw[3] << 16);
        ph.z = hw[4] | (hw[5] << 16); ph.w = hw[6] | (hw[7] << 16);
        pl.x = lw[0] | (lw[1] << 16); pl.y = lw[2] | (lw[3] << 16);
        pl.z = lw[4] | (lw[5] << 16); pl.w = lw[6] | (lw[7] << 16);
        int off = row * 256 + ((slot ^ (row & 7)) << 4);
        *(uint4*)&xsh[off] = ph;
        *(uint4*)&xsl[off] = pl;
    }
    // stage Mt (32 KB, L2-hot), same swizzle
    #pragma unroll
    for (int it = 0; it < 8; ++it) {
        int idx = it * 256 + t;
        int row = idx >> 4, slot = idx & 15;
        uint4 mv = ((const uint4*)Mt)[idx];
        *(uint4*)&mts[row * 256 + ((slot ^ (row & 7)) << 4)] = mv;
    }
    __syncthreads();

    int w = t >> 6;                 // wave id: rows w*16..w*16+15
    int lidx = t & 15;              // lane&15
    int grp = (t >> 4) & 3;         // lane>>4 within wave
    f32x4 acc[8];
    #pragma unroll
    for (int nt = 0; nt < 8; ++nt) acc[nt] = (f32x4){0.f, 0.f, 0.f, 0.f};

    #pragma unroll
    for (int ks = 0; ks < 4; ++ks) {
        int arow = w * 16 + lidx;
        int slot = ks * 4 + grp;
        bf16x8 ah = *(bf16x8*)&xsh[arow * 256 + ((slot ^ (arow & 7)) << 4)];
        bf16x8 al = *(bf16x8*)&xsl[arow * 256 + ((slot ^ (arow & 7)) << 4)];
        #pragma unroll
        for (int nt = 0; nt < 8; ++nt) {
            int brow = nt * 16 + lidx;
            bf16x8 bb = *(bf16x8*)&mts[brow * 256 + ((slot ^ (brow & 7)) << 4)];
            acc[nt] = __builtin_amdgcn_mfma_f32_16x16x32_bf16(al, bb, acc[nt], 0, 0, 0);
            acc[nt] = __builtin_amdgcn_mfma_f32_16x16x32_bf16(ah, bb, acc[nt], 0, 0, 0);
        }
    }

    float bias[8];
    #pragma unroll
    for (int nt = 0; nt < 8; ++nt) bias[nt] = b1[nt * 16 + lidx];

    // epilogue: relu -> mean/std (16-lane group = one row) -> z -> LDS (bf16)
    #pragma unroll
    for (int r = 0; r < 4; ++r) {
        int row_loc = w * 16 + grp * 4 + r;
        float v[8];
        float s = 0.f;
        #pragma unroll
        for (int nt = 0; nt < 8; ++nt) {
            float x = acc[nt][r] + bias[nt];
            x = x > 0.f ? x : 0.f;
            v[nt] = x;
            s += x;
        }
        s += __shfl_xor(s, 1); s += __shfl_xor(s, 2);
        s += __shfl_xor(s, 4); s += __shfl_xor(s, 8);
        float mean = s * (1.0f / 128.0f);
        float q = 0.f;
        #pragma unroll
        for (int nt = 0; nt < 8; ++nt) {
            float d = v[nt] - mean;
            v[nt] = d;
            q += d * d;
        }
        q += __shfl_xor(q, 1); q += __shfl_xor(q, 2);
        q += __shfl_xor(q, 4); q += __shfl_xor(q, 8);
        float inv = 0.f;
        if (q > 0.f) inv = 1.0f / sqrtf(q * (1.0f / 127.0f));
        #pragma unroll
        for (int nt = 0; nt < 8; ++nt)
            *(unsigned short*)&xsh[row_loc * 256 + (nt * 16 + lidx) * 2] = f2bf(v[nt] * inv);
    }
    __syncthreads();

    // coalesced writeout: bf16 row-linear + fp8 shadow
    #pragma unroll
    for (int it = 0; it < 4; ++it) {
        int idx = it * 256 + t;
        int row = idx >> 4, slot = idx & 15;
        if (row < rows_this) {
            uint4 zv = *(uint4*)&xsh[row * 256 + slot * 16];
            *(uint4*)(xbf + (row0 + row) * 128 + slot * 8) = zv;
            uint2 p8;
            p8.x = pk_fp8x4(bflo(zv.x), bfhi(zv.x), bflo(zv.y), bfhi(zv.y));
            p8.y = pk_fp8x4(bflo(zv.z), bfhi(zv.z), bflo(zv.w), bfhi(zv.w));
            *(uint2*)(x8 + (row0 + row) * 128 + slot * 8) = p8;
        }
    }
}

// ---------------- CSR build (unified, N rows, global cols) ----------------
__global__ __launch_bounds__(256) void count_rows(const int* __restrict__ rows, int E,
                                                  int* __restrict__ cnt) {
    int i = (blockIdx.x * 256 + threadIdx.x) * 4;
    if (i + 4 <= E) {
        int4 r = *(const int4*)(rows + i);
        atomicAdd(&cnt[r.x], 1);
        atomicAdd(&cnt[r.y], 1);
        atomicAdd(&cnt[r.z], 1);
        atomicAdd(&cnt[r.w], 1);
    } else {
        for (; i < E; ++i) atomicAdd(&cnt[rows[i]], 1);
    }
}

__global__ __launch_bounds__(256) void scan1(const int* __restrict__ cnt, int R,
                                             int* __restrict__ rp, int* __restrict__ bt) {
    __shared__ int lds[256];
    int t = threadIdx.x, b = blockIdx.x;
    int base = b * 4096 + t * 16;
    int v[16];
    int s = 0;
    #pragma unroll
    for (int i = 0; i < 16; ++i) {
        int idx = base + i;
        int c = (idx < R) ? cnt[idx] : 0;
        v[i] = s;
        s += c;
    }
    lds[t] = s;
    __syncthreads();
    for (int off = 1; off < 256; off <<= 1) {
        int x = (t >= off) ? lds[t - off] : 0;
        __syncthreads();
        lds[t] += x;
        __syncthreads();
    }
    int excl = lds[t] - s;
    #pragma unroll
    for (int i = 0; i < 16; ++i) {
        int idx = base + i;
        if (idx < R) rp[idx] = excl + v[i];
    }
    if (t == 0) bt[b] = lds[255];
}

__global__ __launch_bounds__(64) void scan2(const int* __restrict__ bt, int B,
                                            int* __restrict__ bo, int* __restrict__ rp,
                                            int R, int E2) {
    int t = threadIdx.x;
    int v = (t < B) ? bt[t] : 0;
    int inc = v;
    #pragma unroll
    for (int off = 1; off < 64; off <<= 1) {
        int y = __shfl_up(inc, off);
        if (t >= off) inc += y;
    }
    if (t < B) bo[t] = inc - v;
    if (t == 0) rp[R] = E2;
}

__global__ __launch_bounds__(256) void scan3(int* __restrict__ rp, const int* __restrict__ bo,
                                             int R) {
    int i = blockIdx.x * 256 + threadIdx.x;
    if (i < R) rp[i] = rp[i] + bo[i >> 12];
}

__global__ __launch_bounds__(256) void binit(const int* __restrict__ rp, int NR,
                                             int nbuck, int* __restrict__ bcur) {
    int b = blockIdx.x * 256 + threadIdx.x;
    if (b < nbuck) {
        int r = b << 9;
        if (r > NR) r = NR;
        bcur[b] = rp[r];
    }
}

// ---- phase 1: partition edges into 512-row buckets (L2-local writes) ----
__global__ __launch_bounds__(256) void partition_edges(const int* __restrict__ rows,
                                                       const int* __restrict__ cols,
                                                       const float* __restrict__ vals,
                                                       int E, int nbuck,
                                                       int* __restrict__ bcur,
                                                       int2* __restrict__ tmp) {
    __shared__ int hist[512];
    __shared__ int gbase[512];
    __shared__ int cnt2[512];
    int t = threadIdx.x;
    for (int b = t; b < nbuck; b += 256) { hist[b] = 0; cnt2[b] = 0; }
    __syncthreads();
    long base = (long)blockIdx.x * 4096;
    #pragma unroll
    for (int k = 0; k < 16; ++k) {
        long i = base + k * 256 + t;
        if (i < E) atomicAdd(&hist[rows[i] >> 9], 1);
    }
    __syncthreads();
    for (int b = t; b < nbuck; b += 256) {
        int h = hist[b];
        gbase[b] = h ? atomicAdd(&bcur[b], h) : 0;
    }
    __syncthreads();
    #pragma unroll
    for (int k = 0; k < 16; ++k) {
        long i = base + k * 256 + t;
        if (i < E) {
            int rl = rows[i];
            int b = rl >> 9;
            int rank = atomicAdd(&cnt2[b], 1);
            int2 rec;
            rec.x = ((rl - (b << 9)) << 18) | cols[i];
            rec.y = __float_as_int(vals[i]);
            tmp[gbase[b] + rank] = rec;
        }
    }
}

// ---- phase 2: exact-position scatter within one bucket, LDS atomics only ----
__global__ __launch_bounds__(1024) void place_edges(const int* __restrict__ rp,
                                                    const int2* __restrict__ tmp,
                                                    int NR,
                                                    int2* __restrict__ scv) {
    __shared__ int hist[512];
    __shared__ int hoff[512];
    int b = blockIdx.x;
    int srow = b << 9;
    int erow = srow + 512;
    if (erow > NR) erow = NR;
    int start = rp[srow], endp = rp[erow];
    int t = threadIdx.x;
    if (t < 512) hist[t] = 0;
    __syncthreads();

    for (int i = start + t; i < endp; i += 1024)
        atomicAdd(&hist[tmp[i].x >> 18], 1);
    __syncthreads();

    if (t < 512) hoff[t] = hist[t];
    __syncthreads();
    for (int off = 1; off < 512; off <<= 1) {
        int v = 0;
        if (t < 512 && t >= off) v = hoff[t - off];
        __syncthreads();
        if (t < 512) hoff[t] += v;
        __syncthreads();
    }
    if (t < 512) hoff[t] = start + hoff[t] - hist[t];
    __syncthreads();

    int i = start + t;
    for (; i + 3 * 1024 < endp; i += 4 * 1024) {
        int2 a0 = tmp[i];
        int2 a1 = tmp[i + 1024];
        int2 a2 = tmp[i + 2048];
        int2 a3 = tmp[i + 3072];
        int p0 = atomicAdd(&hoff[a0.x >> 18], 1);
        int p1 = atomicAdd(&hoff[a1.x >> 18], 1);
        int p2 = atomicAdd(&hoff[a2.x >> 18], 1);
        int p3 = atomicAdd(&hoff[a3.x >> 18], 1);
        int2 o0; o0.x = a0.x & 0x3ffff; o0.y = a0.y;
        int2 o1; o1.x = a1.x & 0x3ffff; o1.y = a1.y;
        int2 o2; o2.x = a2.x & 0x3ffff; o2.y = a2.y;
        int2 o3; o3.x = a3.x & 0x3ffff; o3.y = a3.y;
        scv[p0] = o0;
        scv[p1] = o1;
        scv[p2] = o2;
        scv[p3] = o3;
    }
    for (; i < endp; i += 1024) {
        int2 rec = tmp[i];
        int p = atomicAdd(&hoff[rec.x >> 18], 1);
        int2 o;
        o.x = rec.x & 0x3ffff;
        o.y = rec.y;
        scv[p] = o;
    }
}

// decode one fp8 row-segment (8 vals in uint2) and packed-fma into acc[4]
#define DEC_FMA(qq, vv) do {                                                        \
    f32x2 vp_ = {(vv), (vv)};                                                       \
    acc[0] = __builtin_elementwise_fma(vp_, __builtin_amdgcn_cvt_pk_f32_fp8((qq).x, false), acc[0]); \
    acc[1] = __builtin_elementwise_fma(vp_, __builtin_amdgcn_cvt_pk_f32_fp8((qq).x, true),  acc[1]); \
    acc[2] = __builtin_elementwise_fma(vp_, __builtin_amdgcn_cvt_pk_f32_fp8((qq).y, false), acc[2]); \
    acc[3] = __builtin_elementwise_fma(vp_, __builtin_amdgcn_cvt_pk_f32_fp8((qq).y, true),  acc[3]); \
} while (0)

// ---- SpMM core: one row per 16-lane quarter, unroll x8, fp8 gathers ----
__device__ inline void spmm_core8(const int* __restrict__ rp,
                                  const int2* __restrict__ scv,
                                  const unsigned char* __restrict__ g8,
                                  int row, int f, f32x2* acc) {
    int beg = rp[row], end = rp[row + 1];
    int j = beg;
    if ((j & 1) && j < end) {
        int2 r0 = scv[j];
        uint2 q0 = *(const uint2*)(g8 + ((long)r0.x << 7) + f);
        float v0 = __int_as_float(r0.y);
        DEC_FMA(q0, v0);
        ++j;
    }
    for (; j + 8 <= end; j += 8) {
        int4 s01 = *(const int4*)(scv + j);
        int4 s23 = *(const int4*)(scv + j + 2);
        int4 s45 = *(const int4*)(scv + j + 4);
        int4 s67 = *(const int4*)(scv + j + 6);
        uint2 q0 = *(const uint2*)(g8 + ((long)s01.x << 7) + f);
        uint2 q1 = *(const uint2*)(g8 + ((long)s01.z << 7) + f);
        uint2 q2 = *(const uint2*)(g8 + ((long)s23.x << 7) + f);
        uint2 q3 = *(const uint2*)(g8 + ((long)s23.z << 7) + f);
        uint2 q4 = *(const uint2*)(g8 + ((long)s45.x << 7) + f);
        uint2 q5 = *(const uint2*)(g8 + ((long)s45.z << 7) + f);
        uint2 q6 = *(const uint2*)(g8 + ((long)s67.x << 7) + f);
        uint2 q7 = *(const uint2*)(g8 + ((long)s67.z << 7) + f);
        DEC_FMA(q0, __int_as_float(s01.y));
        DEC_FMA(q1, __int_as_float(s01.w));
        DEC_FMA(q2, __int_as_float(s23.y));
        DEC_FMA(q3, __int_as_float(s23.w));
        DEC_FMA(q4, __int_as_float(s45.y));
        DEC_FMA(q5, __int_as_float(s45.w));
        DEC_FMA(q6, __int_as_float(s67.y));
        DEC_FMA(q7, __int_as_float(s67.w));
    }
    for (; j + 2 <= end; j += 2) {
        int4 s01 = *(const int4*)(scv + j);
        uint2 q0 = *(const uint2*)(g8 + ((long)s01.x << 7) + f);
        uint2 q1 = *(const uint2*)(g8 + ((long)s01.z << 7) + f);
        DEC_FMA(q0, __int_as_float(s01.y));
        DEC_FMA(q1, __int_as_float(s01.w));
    }
    if (j < end) {
        int2 r0 = scv[j];
        uint2 q0 = *(const uint2*)(g8 + ((long)r0.x << 7) + f);
        float v0 = __int_as_float(r0.y);
        DEC_FMA(q0, v0);
    }
}

// h = M @ X : gathers X8 (fp8), writes h as bf16 (stream copy) + fp8 (gather copy)
__global__ __launch_bounds__(256) void spmm_plain(const int* __restrict__ rp,
                                                  const int2* __restrict__ scv,
                                                  const unsigned char* __restrict__ x8,
                                                  unsigned short* __restrict__ houtbf,
                                                  unsigned char* __restrict__ hout8,
                                                  int R) {
    int wave = blockIdx.x * 4 + (threadIdx.x >> 6);
    int lane = threadIdx.x & 63;
    int row = wave * 4 + (lane >> 4);
    if (row >= R) return;
    int f = (lane & 15) << 3;
    f32x2 acc[4];
    #pragma unroll
    for (int i = 0; i < 4; ++i) acc[i] = (f32x2){0.f, 0.f};
    spmm_core8(rp, scv, x8, row, f, acc);
    uint4 o;
    o.x = (unsigned)f2bf(acc[0].x) | ((unsigned)f2bf(acc[0].y) << 16);
    o.y = (unsigned)f2bf(acc[1].x) | ((unsigned)f2bf(acc[1].y) << 16);
    o.z = (unsigned)f2bf(acc[2].x) | ((unsigned)f2bf(acc[2].y) << 16);
    o.w = (unsigned)f2bf(acc[3].x) | ((unsigned)f2bf(acc[3].y) << 16);
    *(uint4*)(houtbf + ((long)row << 7) + f) = o;
    uint2 o8;
    o8.x = pk_fp8x4(acc[0].x, acc[0].y, acc[1].x, acc[1].y);
    o8.y = pk_fp8x4(acc[2].x, acc[2].y, acc[3].x, acc[3].y);
    *(uint2*)(hout8 + ((long)row << 7) + f) = o8;
}

// pass-1 update: X = c0*X + c_h[seg]*h + c_2nd[seg]*(M @ h)
__global__ __launch_bounds__(256) void spmm_update(const int* __restrict__ rp,
                                                   const int2* __restrict__ scv,
                                                   const unsigned char* __restrict__ h8,
                                                   const unsigned short* __restrict__ hbf,
                                                   unsigned short* __restrict__ Xbf,
                                                   unsigned char* __restrict__ X8,
                                                   const float* __restrict__ coe,
                                                   int ihA, int iaA, int ihP, int iaP,
                                                   int NA, int R) {
    int wave = blockIdx.x * 4 + (threadIdx.x >> 6);
    int lane = threadIdx.x & 63;
    int row = wave * 4 + (lane >> 4);
    if (row >= R) return;
    int f = (lane & 15) << 3;
    f32x2 acc[4];
    #pragma unroll
    for (int i = 0; i < 4; ++i) acc[i] = (f32x2){0.f, 0.f};
    spmm_core8(rp, scv, h8, row, f, acc);

    float c0 = coe[0];
    float ch = coe[row < NA ? ihA : ihP];
    float ca = coe[row < NA ? iaA : iaP];
    long o = ((long)row << 7) + f;
    uint4 xv = *(const uint4*)(Xbf + o);
    uint4 hs = *(const uint4*)(hbf + o);
    float r[8];
    r[0] = c0 * bflo(xv.x) + ch * bflo(hs.x) + ca * acc[0].x;
    r[1] = c0 * bfhi(xv.x) + ch * bfhi(hs.x) + ca * acc[0].y;
    r[2] = c0 * bflo(xv.y) + ch * bflo(hs.y) + ca * acc[1].x;
    r[3] = c0 * bfhi(xv.y) + ch * bfhi(hs.y) + ca * acc[1].y;
    r[4] = c0 * bflo(xv.z) + ch * bflo(hs.z) + ca * acc[2].x;
    r[5] = c0 * bfhi(xv.z) + ch * bfhi(hs.z) + ca * acc[2].y;
    r[6] = c0 * bflo(xv.w) + ch * bflo(hs.w) + ca * acc[3].x;
    r[7] = c0 * bfhi(xv.w) + ch * bfhi(hs.w) + ca * acc[3].y;
    uint4 ob;
    ob.x = (unsigned)f2bf(r[0]) | ((unsigned)f2bf(r[1]) << 16);
    ob.y = (unsigned)f2bf(r[2]) | ((unsigned)f2bf(r[3]) << 16);
    ob.z = (unsigned)f2bf(r[4]) | ((unsigned)f2bf(r[5]) << 16);
    ob.w = (unsigned)f2bf(r[6]) | ((unsigned)f2bf(r[7]) << 16);
    *(uint4*)(Xbf + o) = ob;
    uint2 o8;
    o8.x = pk_fp8x4(r[0], r[1], r[2], r[3]);
    o8.y = pk_fp8x4(r[4], r[5], r[6], r[7]);
    *(uint2*)(X8 + o) = o8;
}

// pass-2 update fused with final GEMM
__global__ __launch_bounds__(256) void spmm_update_out(const int* __restrict__ rp,
                                                       const int2* __restrict__ scv,
                                                       const unsigned char* __restrict__ h8,
                                                       const unsigned short* __restrict__ hbf,
                                                       const unsigned short* __restrict__ Xbf,
                                                       const float* __restrict__ coe,
                                                       const float* __restrict__ W2,
                                                       const float* __restrict__ b2,
                                                       float* __restrict__ out,
                                                       int ihA, int iaA, int ihP, int iaP,
                                                       int NA, int R) {
    __shared__ float xs[16 * 132];
    __shared__ float wT[16 * 132];   // wT[c][k] = W2[k][c]
    __shared__ float bs[16];
    int t = threadIdx.x;
    #pragma unroll
    for (int i = 0; i < 8; ++i) {
        int idx = i * 256 + t;                // 2048 = 128*16
        wT[(idx & 15) * 132 + (idx >> 4)] = W2[idx];
    }
    if (t < 16) bs[t] = b2[t];

    int lane = t & 63;
    int rl = (t >> 6) * 4 + (lane >> 4);
    int row = blockIdx.x * 16 + rl;
    int f = (lane & 15) << 3;
    if (row < R) {
        f32x2 acc[4];
        #pragma unroll
        for (int i = 0; i < 4; ++i) acc[i] = (f32x2){0.f, 0.f};
        spmm_core8(rp, scv, h8, row, f, acc);
        float c0 = coe[0];
        float ch = coe[row < NA ? ihA : ihP];
        float ca = coe[row < NA ? iaA : iaP];
        long o = ((long)row << 7) + f;
        uint4 xv = *(const uint4*)(Xbf + o);
        uint4 hs = *(const uint4*)(hbf + o);
        float* x = &xs[rl * 132 + f];
        x[0] = c0 * bflo(xv.x) + ch * bflo(hs.x) + ca * acc[0].x;
        x[1] = c0 * bfhi(xv.x) + ch * bfhi(hs.x) + ca * acc[0].y;
        x[2] = c0 * bflo(xv.y) + ch * bflo(hs.y) + ca * acc[1].x;
        x[3] = c0 * bfhi(xv.y) + ch * bfhi(hs.y) + ca * acc[1].y;
        x[4] = c0 * bflo(xv.z) + ch * bflo(hs.z) + ca * acc[2].x;
        x[5] = c0 * bfhi(xv.z) + ch * bfhi(hs.z) + ca * acc[2].y;
        x[6] = c0 * bflo(xv.w) + ch * bflo(hs.w) + ca * acc[3].x;
        x[7] = c0 * bfhi(xv.w) + ch * bfhi(hs.w) + ca * acc[3].y;
    }
    __syncthreads();
    int orl = t >> 4, c = t & 15;
    long orow = (long)blockIdx.x * 16 + orl;
    if (orow < R) {
        const float* xrow = &xs[orl * 132];
        const float* wrow = &wT[c * 132];
        f32x4 a4 = {0.f, 0.f, 0.f, 0.f};
        #pragma unroll 8
        for (int k = 0; k < 128; k += 4) {
            f32x4 xv = *(const f32x4*)(xrow + k);
            f32x4 wv = *(const f32x4*)(wrow + k);
            a4 = __builtin_elementwise_fma(xv, wv, a4);
        }
        out[orow * 16 + c] = a4.x + a4.y + a4.z + a4.w + bs[c];
    }
}

extern "C" void kernel_launch(void* const* d_in, const int* in_sizes, int n_in,
                              void* d_out, int out_size, void* d_ws, size_t ws_size,
                              hipStream_t stream) {
    const float* x0  = (const float*)d_in[0];
    const float* x1  = (const float*)d_in[1];
    const float* vap = (const float*)d_in[2];
    const float* vpa = (const float*)d_in[3];
    const int*   rap = (const int*)d_in[4];
    const int*   cap = (const int*)d_in[5];
    const int*   rpa = (const int*)d_in[6];
    const int*   cpa = (const int*)d_in[7];
    const float* Wp0 = (const float*)d_in[8];
    const float* Wp1 = (const float*)d_in[9];
    const float* W1  = (const float*)d_in[10];
    const float* b1  = (const float*)d_in[11];
    const float* W2  = (const float*)d_in[12];
    const float* b2  = (const float*)d_in[13];
    const float* coe = (const float*)d_in[14];
    float* out = (float*)d_out;

    const int NA = in_sizes[0] / 128;
    const int NP = in_sizes[1] / 128;
    const int N  = NA + NP;
    const int E  = in_sizes[2];
    const int E2 = 2 * E;

    char* p = (char*)d_ws;
    auto alloc = [&](size_t bytes) {
        char* r = p;
        p += (bytes + 255) & ~(size_t)255;
        return r;
    };
    unsigned short* Xbf = (unsigned short*)alloc((size_t)N * 128 * 2);
    unsigned short* hbf = (unsigned short*)alloc((size_t)N * 128 * 2);
    unsigned char* X8 = (unsigned char*)alloc((size_t)N * 128);
    unsigned char* h8 = (unsigned char*)alloc((size_t)N * 128);
    unsigned short* Mt0 = (unsigned short*)alloc(128 * 128 * 2);
    unsigned short* Mt1 = (unsigned short*)alloc(128 * 128 * 2);
    int* cnt   = (int*)alloc((size_t)N * 4);
    int* rp    = (int*)alloc((size_t)(N + 1) * 4);
    int* bt    = (int*)alloc(64 * 4);
    int* bo    = (int*)alloc(64 * 4);
    int2* scv  = (int2*)alloc((size_t)E2 * 8);
    int* bcur  = (int*)alloc(512 * 4);
    if ((size_t)(p - (char*)d_ws) > ws_size) return;

    // tmp partition buffer aliases Xbf (Xbf written only after CSR build);
    // E2*8 = 32 MB <= N*256B = 64 MB
    int2* tmp = (int2*)Xbf;

    const int nbuck = (N + 511) >> 9;
    const int pg = (E + 4095) / 4096;

    // ---- unified CSR build ----
    hipMemsetAsync(cnt, 0, (size_t)N * 4, stream);
    const int cg = (E / 4 + 255) / 256;
    count_rows<<<cg, 256, 0, stream>>>(rap, E, cnt);
    count_rows<<<cg, 256, 0, stream>>>(rpa, E, cnt);
    int B = (N + 4095) / 4096;
    scan1<<<B, 256, 0, stream>>>(cnt, N, rp, bt);
    scan2<<<1, 64, 0, stream>>>(bt, B, bo, rp, N, E2);
    scan3<<<(N + 255) / 256, 256, 0, stream>>>(rp, bo, N);
    binit<<<2, 256, 0, stream>>>(rp, N, nbuck, bcur);
    partition_edges<<<pg, 256, 0, stream>>>(rap, cap, vap, E, nbuck, bcur, tmp);
    partition_edges<<<pg, 256, 0, stream>>>(rpa, cpa, vpa, E, nbuck, bcur, tmp);
    place_edges<<<nbuck, 1024, 0, stream>>>(rp, tmp, N, scv);

    // ---- dense front-end (MFMA; Xbf written AFTER tmp aliasing done) ----
    fuse_w<<<256, 128, 0, stream>>>(Wp0, Wp1, W1, Mt0, Mt1);
    gemm_relu_norm<<<(NA + 63) / 64, 256, 0, stream>>>(x0, Mt0, b1, Xbf, X8, NA);
    gemm_relu_norm<<<(NP + 63) / 64, 256, 0, stream>>>(
        x1, Mt1, b1, Xbf + (size_t)NA * 128, X8 + (size_t)NA * 128, NP);

    const int sg = (N + 15) / 16;

    // ---- pass 1 (AP first): A rows coe1/coe3, P rows coe2/coe4 ----
    spmm_plain<<<sg, 256, 0, stream>>>(rp, scv, X8, hbf, h8, N);
    spmm_update<<<sg, 256, 0, stream>>>(rp, scv, h8, hbf, Xbf, X8, coe, 1, 3, 2, 4, NA, N);

    // ---- pass 2 (PA first) fused with out = res2 @ W2 + b2 ----
    spmm_plain<<<sg, 256, 0, stream>>>(rp, scv, X8, hbf, h8, N);
    spmm_update_out<<<sg, 256, 0, stream>>>(rp, scv, h8, hbf, Xbf, coe,
                                            W2, b2, out, 2, 4, 1, 3, NA, N);
}